// Round 1
// 3866.223 us; speedup vs baseline: 1.0211x; 1.0211x over previous
//
#include <hip/hip_runtime.h>
#include <hip/hip_bf16.h>
#include <math.h>

#define L_ 6
#define H_ 16
#define D_ 1024
#define V_ 50257
#define B_ 2
#define T_ 1024
#define M_ (B_*T_)

typedef unsigned short u16;
typedef __attribute__((ext_vector_type(8))) __bf16 bf16x8;
typedef __attribute__((ext_vector_type(4))) float f32x4;

__device__ __forceinline__ u16 f2bf(float x){
  union { __hip_bfloat16 h; u16 u; } c;
  c.h = __float2bfloat16(x);
  return c.u;
}

__device__ __forceinline__ void gload_lds16(const void* g, void* l){
  __builtin_amdgcn_global_load_lds(
      (__attribute__((address_space(1))) void*)(const_cast<void*>(g)),
      (__attribute__((address_space(3))) void*)l, 16, 0, 0);
}

// ---------------- fp32 -> bf16 weight conversion ----------------
__global__ void cvt_bf16x4(const float4* __restrict__ in, ushort4* __restrict__ out, int n4){
  int i = blockIdx.x*256 + threadIdx.x;
  if (i < n4){
    float4 v = in[i];
    ushort4 o;
    o.x = f2bf(v.x); o.y = f2bf(v.y); o.z = f2bf(v.z); o.w = f2bf(v.w);
    out[i] = o;
  }
}

// ---------------- embedding ----------------
__global__ void embed_k(const int* __restrict__ idx, const float* __restrict__ wte,
                        const float* __restrict__ wpe, float* __restrict__ xb){
  int m = blockIdx.x;
  int t = m % T_;
  int tok = idx[m];
  const float* w = wte + (size_t)tok*D_;
  const float* p = wpe + (size_t)t*D_;
  float* o = xb + (size_t)m*D_;
  for (int d = threadIdx.x; d < D_; d += 256) o[d] = w[d] + p[d];
}

// ---------------- layernorm (fp32 in, bf16 out) ----------------
__global__ __launch_bounds__(256) void ln_k(const float* __restrict__ x, const float* __restrict__ w,
                     const float* __restrict__ b, u16* __restrict__ out){
  __shared__ float sm[8];
  int m = blockIdx.x, t = threadIdx.x;
  const float4* xr = (const float4*)(x + (size_t)m*D_);
  float4 v = xr[t];
  float s  = v.x+v.y+v.z+v.w;
  float ss = v.x*v.x+v.y*v.y+v.z*v.z+v.w*v.w;
  for (int o=32;o;o>>=1){ s += __shfl_down(s,o,64); ss += __shfl_down(ss,o,64); }
  if ((t&63)==0){ sm[t>>6]=s; sm[4+(t>>6)]=ss; }
  __syncthreads();
  s  = sm[0]+sm[1]+sm[2]+sm[3];
  ss = sm[4]+sm[5]+sm[6]+sm[7];
  float mean = s*(1.0f/D_);
  float var  = ss*(1.0f/D_) - mean*mean;
  float rstd = rsqrtf(var + 1e-5f);
  float4 wv = ((const float4*)w)[t];
  float4 bv = ((const float4*)b)[t];
  ushort4 o4;
  o4.x = f2bf((v.x-mean)*rstd*wv.x + bv.x);
  o4.y = f2bf((v.y-mean)*rstd*wv.y + bv.y);
  o4.z = f2bf((v.z-mean)*rstd*wv.z + bv.z);
  o4.w = f2bf((v.w-mean)*rstd*wv.w + bv.w);
  ((ushort4*)(out + (size_t)m*D_))[t] = o4;
}

// ---------------- GEMM: C[M,N] = A[M,K] * W[N,K]^T (+bias)(+resid)(gelu) ----------------
// m97 structure: 128x128 tile, 4 waves, mfma_f32_16x16x32_bf16, BK=64, global_load_lds w16.
// Grid: x = M-tiles (fast axis), y = N-tiles. Consecutive blocks share one W-strip
// so a resident wave of blocks keeps its W working set L2/LLC-resident and W streams
// from HBM once (lm-head was re-fetching W ~8x with the old N-fast ordering).
__device__ __forceinline__ void storeval(float* C, size_t i, float v){ C[i] = v; }
__device__ __forceinline__ void storeval(u16*   C, size_t i, float v){ C[i] = f2bf(v); }

template<int KIND, typename OUT_T, bool NB>
__global__ __launch_bounds__(256) void gemm_bt(const u16* __restrict__ A, const u16* __restrict__ W,
    const float* __restrict__ bias, const float* __restrict__ resid,
    OUT_T* __restrict__ C, int M, int N, int K)
{
  __shared__ u16 lA[128*64];
  __shared__ u16 lB[128*64];
  int t = threadIdx.x;
  int m0 = blockIdx.x*128, n0 = blockIdx.y*128;
  int w = t>>6, lane = t&63, quad = lane>>4, lm = lane&15;
  int wr = w>>1, wc = w&1;
  int arow = t>>3, aseg = t&7;
  f32x4 acc[4][4] = {};
  for (int k0 = 0; k0 < K; k0 += 64){
    __syncthreads();
    #pragma unroll
    for (int it=0; it<4; it++){
      gload_lds16(A + (size_t)(m0 + it*32 + arow)*K + k0 + aseg*8, &lA[it*2048 + t*8]);
      int br = n0 + it*32 + arow;
      if (NB) br = (br < N) ? br : (N-1);
      gload_lds16(W + (size_t)br*K + k0 + aseg*8, &lB[it*2048 + t*8]);
    }
    __syncthreads();
    #pragma unroll
    for (int kk=0; kk<64; kk+=32){
      bf16x8 af[4], bfr[4];
      #pragma unroll
      for (int i=0;i<4;i++) af[i]  = *(const bf16x8*)&lA[(wr*64+i*16+lm)*64 + kk + quad*8];
      #pragma unroll
      for (int j=0;j<4;j++) bfr[j] = *(const bf16x8*)&lB[(wc*64+j*16+lm)*64 + kk + quad*8];
      #pragma unroll
      for (int i=0;i<4;i++)
        #pragma unroll
        for (int j=0;j<4;j++)
          acc[i][j] = __builtin_amdgcn_mfma_f32_16x16x32_bf16(af[i], bfr[j], acc[i][j], 0,0,0);
    }
  }
  #pragma unroll
  for (int i=0;i<4;i++){
    int mb = m0 + wr*64 + i*16 + quad*4;
    #pragma unroll
    for (int j=0;j<4;j++){
      int n = n0 + wc*64 + j*16 + lm;
      if (NB && n >= N) continue;
      float bv = bias ? bias[n] : 0.0f;
      #pragma unroll
      for (int r=0;r<4;r++){
        float v = acc[i][j][r] + bv;
        int mm = mb + r;
        if (KIND==1) v += resid[(size_t)mm*N + n];
        if (KIND==2) v = 0.5f*v*(1.0f + erff(v*0.70710678118654752f));
        storeval(C, (size_t)mm*(size_t)N + n, v);
      }
    }
  }
}

// ---------------- attention: S = scale*Q K^T (causal tiles only) ----------------
__global__ __launch_bounds__(256) void qk_k(const float* __restrict__ qkv, float* __restrict__ S){
  __shared__ float lQ[64][68];
  __shared__ float lK[64][68];
  int blk = blockIdx.x;
  int qt = blk & 15, bh = blk >> 4;
  int b = bh >> 4, h = bh & 15;
  int t = threadIdx.x;
  int qi = t >> 4, ki = t & 15;
  const float* qbase = qkv + (size_t)b*T_*3072 + h*64;
  for (int idx=t; idx<4096; idx+=256){
    int r = idx>>6, d = idx&63;
    lQ[r][d] = qbase[(size_t)(qt*64+r)*3072 + d];
  }
  float* Srow = S + ((size_t)bh*T_ + qt*64)*T_;
  for (int kt=0; kt<=qt; kt++){
    __syncthreads();
    for (int idx=t; idx<4096; idx+=256){
      int r = idx>>6, d = idx&63;
      lK[r][d] = qbase[(size_t)(kt*64+r)*3072 + 1024 + d];
    }
    __syncthreads();
    float acc[4][4] = {};
    for (int d=0; d<64; d+=4){
      float4 qv[4], kv[4];
      #pragma unroll
      for (int a=0;a<4;a++) qv[a] = *(const float4*)&lQ[qi*4+a][d];
      #pragma unroll
      for (int c=0;c<4;c++) kv[c] = *(const float4*)&lK[c*16+ki][d];
      #pragma unroll
      for (int a=0;a<4;a++)
        #pragma unroll
        for (int c=0;c<4;c++)
          acc[a][c] += qv[a].x*kv[c].x + qv[a].y*kv[c].y + qv[a].z*kv[c].z + qv[a].w*kv[c].w;
    }
    #pragma unroll
    for (int a=0;a<4;a++){
      int q = qt*64 + qi*4 + a;
      #pragma unroll
      for (int c=0;c<4;c++){
        int k = kt*64 + c*16 + ki;
        Srow[(size_t)(qi*4+a)*T_ + k] = (k<=q) ? acc[a][c]*0.125f : -1e30f;
      }
    }
  }
}

// ---------------- causal-prefix softmax over rows of S ----------------
__global__ __launch_bounds__(256) void softmax_k(float* __restrict__ S){
  __shared__ float sm[8];
  int row = blockIdx.x;
  int q = row & (T_-1);
  int len = ((q>>6)+1)*64;
  float* p = S + (size_t)row*T_;
  int t = threadIdx.x;
  float v[4];
  float mx = -1e30f;
  #pragma unroll
  for (int r=0;r<4;r++){
    int i = t + r*256;
    v[r] = (i<len) ? p[i] : -1e30f;
    mx = fmaxf(mx, v[r]);
  }
  for (int o=32;o;o>>=1) mx = fmaxf(mx, __shfl_down(mx,o,64));
  if ((t&63)==0) sm[t>>6]=mx;
  __syncthreads();
  mx = fmaxf(fmaxf(sm[0],sm[1]), fmaxf(sm[2],sm[3]));
  float s = 0.f;
  #pragma unroll
  for (int r=0;r<4;r++){
    int i = t + r*256;
    v[r] = (i<len) ? expf(v[r]-mx) : 0.f;
    s += v[r];
  }
  for (int o=32;o;o>>=1) s += __shfl_down(s,o,64);
  if ((t&63)==0) sm[4+(t>>6)]=s;
  __syncthreads();
  s = sm[4]+sm[5]+sm[6]+sm[7];
  float inv = 1.0f/s;
  #pragma unroll
  for (int r=0;r<4;r++){
    int i = t + r*256;
    if (i<len) p[i] = v[r]*inv;
  }
}

// ---------------- y = P V (bf16 out into activation buffer) ----------------
__global__ __launch_bounds__(256) void pv_k(const float* __restrict__ S, const float* __restrict__ qkv,
                                            u16* __restrict__ out){
  __shared__ float lP[64][68];
  __shared__ float lVt[64][68];
  int blk = blockIdx.x;
  int qt = blk & 15, bh = blk >> 4;
  int b = bh >> 4, h = bh & 15;
  int t = threadIdx.x;
  int qi = t >> 4, ki = t & 15;
  const float* Sbase = S + ((size_t)bh*T_ + qt*64)*T_;
  const float* vbase = qkv + (size_t)b*T_*3072 + 2048 + h*64;
  float acc[4][4] = {};
  for (int kt=0; kt<=qt; kt++){
    __syncthreads();
    for (int idx=t; idx<4096; idx+=256){
      int r = idx>>6, c = idx&63;
      lP[r][c]  = Sbase[(size_t)r*T_ + kt*64 + c];
      lVt[c][r] = vbase[(size_t)(kt*64+r)*3072 + c];
    }
    __syncthreads();
    for (int k=0;k<64;k+=4){
      float4 pv[4], vv[4];
      #pragma unroll
      for (int a=0;a<4;a++) pv[a] = *(const float4*)&lP[qi*4+a][k];
      #pragma unroll
      for (int c=0;c<4;c++) vv[c] = *(const float4*)&lVt[c*16+ki][k];
      #pragma unroll
      for (int a=0;a<4;a++)
        #pragma unroll
        for (int c=0;c<4;c++)
          acc[a][c] += pv[a].x*vv[c].x + pv[a].y*vv[c].y + pv[a].z*vv[c].z + pv[a].w*vv[c].w;
    }
  }
  size_t obase = (size_t)(b*T_ + qt*64)*D_ + h*64;
  #pragma unroll
  for (int a=0;a<4;a++)
    #pragma unroll
    for (int c=0;c<4;c++)
      out[obase + (size_t)(qi*4+a)*D_ + c*16 + ki] = f2bf(acc[a][c]);
}

// ---------------- loss (single-pass online max/sum: halves logits traffic) ----------------
__global__ __launch_bounds__(256) void loss_row_k(const float* __restrict__ logits,
                                                  const int* __restrict__ targets,
                                                  float* __restrict__ rowloss){
  __shared__ float smx[4], ssm[4];
  int m = blockIdx.x, t = threadIdx.x;
  const float* p = logits + (size_t)m*V_;
  float mx = -1e30f, s = 0.f;
  for (int i=t;i<V_;i+=256){
    float v = p[i];
    if (v > mx){ s = s*expf(mx - v) + 1.0f; mx = v; }
    else        s += expf(v - mx);
  }
  // wave-level combine of (mx, s)
  for (int o=32;o;o>>=1){
    float omx = __shfl_down(mx,o,64);
    float os  = __shfl_down(s,o,64);
    float nm = fmaxf(mx, omx);
    s = s*expf(mx-nm) + os*expf(omx-nm);
    mx = nm;
  }
  if ((t&63)==0){ smx[t>>6]=mx; ssm[t>>6]=s; }
  __syncthreads();
  if (t==0){
    float gm = fmaxf(fmaxf(smx[0],smx[1]), fmaxf(smx[2],smx[3]));
    float gs = ssm[0]*expf(smx[0]-gm) + ssm[1]*expf(smx[1]-gm)
             + ssm[2]*expf(smx[2]-gm) + ssm[3]*expf(smx[3]-gm);
    rowloss[m] = logf(gs) + gm - p[targets[m]];
  }
}

__global__ void loss_reduce_k(const float* __restrict__ rowloss, float* __restrict__ out){
  __shared__ float sm[4];
  int t = threadIdx.x;
  float s = 0.f;
  for (int i=t;i<M_;i+=256) s += rowloss[i];
  for (int o=32;o;o>>=1) s += __shfl_down(s,o,64);
  if ((t&63)==0) sm[t>>6]=s;
  __syncthreads();
  if (t==0) out[0] = (sm[0]+sm[1]+sm[2]+sm[3])*(1.0f/M_);
}

// ---------------- launch ----------------
extern "C" void kernel_launch(void* const* d_in, const int* in_sizes, int n_in,
                              void* d_out, int out_size, void* d_ws, size_t ws_size,
                              hipStream_t stream) {
  const int*   idx     = (const int*)d_in[0];
  const int*   targets = (const int*)d_in[1];
  const float* wte     = (const float*)d_in[2];
  const float* wpe     = (const float*)d_in[3];
  const float* ln1_w   = (const float*)d_in[4];
  const float* ln1_b   = (const float*)d_in[5];
  const float* attn_w  = (const float*)d_in[6];
  const float* attn_b  = (const float*)d_in[7];
  const float* proj_w  = (const float*)d_in[8];
  const float* proj_b  = (const float*)d_in[9];
  const float* ln2_w   = (const float*)d_in[10];
  const float* ln2_b   = (const float*)d_in[11];
  const float* fc_w    = (const float*)d_in[12];
  const float* fc_b    = (const float*)d_in[13];
  const float* fcp_w   = (const float*)d_in[14];
  const float* fcp_b   = (const float*)d_in[15];
  const float* lnf_w   = (const float*)d_in[16];
  const float* lnf_b   = (const float*)d_in[17];

  char* ws = (char*)d_ws;
  size_t off = 0;
  auto alloc = [&](size_t bytes)->void*{ void* p = ws + off; off += (bytes + 255) & ~(size_t)255; return p; };
  u16*   wte_bf  = (u16*)  alloc((size_t)V_*D_*2);
  u16*   aw_bf   = (u16*)  alloc((size_t)L_*3*D_*D_*2);
  u16*   pw_bf   = (u16*)  alloc((size_t)L_*D_*D_*2);
  u16*   fw_bf   = (u16*)  alloc((size_t)L_*4*D_*D_*2);
  u16*   fpw_bf  = (u16*)  alloc((size_t)L_*D_*4*D_*2);
  float* xb      = (float*)alloc((size_t)M_*D_*4);
  u16*   actA    = (u16*)  alloc((size_t)M_*4*D_*2);
  u16*   actB    = (u16*)  alloc((size_t)M_*4*D_*2);
  float* qkvb    = (float*)alloc((size_t)M_*3*D_*4);
  float* scores  = (float*)alloc((size_t)B_*H_*T_*T_*4);
  float* rowloss = (float*)alloc((size_t)M_*4);
  (void)ws_size; (void)in_sizes; (void)n_in; (void)out_size;

  auto cvt = [&](const float* in, u16* out, size_t n){
    int n4 = (int)(n/4);
    cvt_bf16x4<<<dim3((n4+255)/256), dim3(256), 0, stream>>>((const float4*)in, (ushort4*)out, n4);
  };
  cvt(wte,    wte_bf, (size_t)V_*D_);
  cvt(attn_w, aw_bf,  (size_t)L_*3*D_*D_);
  cvt(proj_w, pw_bf,  (size_t)L_*D_*D_);
  cvt(fc_w,   fw_bf,  (size_t)L_*4*D_*D_);
  cvt(fcp_w,  fpw_bf, (size_t)L_*D_*4*D_);

  embed_k<<<M_, 256, 0, stream>>>(idx, wte, wpe, xb);

  for (int l=0; l<L_; l++){
    ln_k<<<M_, 256, 0, stream>>>(xb, ln1_w + l*D_, ln1_b + l*D_, actA);
    gemm_bt<0,float,false><<<dim3(16,24), 256, 0, stream>>>(
        actA, aw_bf + (size_t)l*3*D_*D_, attn_b + l*3*D_, nullptr, qkvb, M_, 3*D_, D_);
    qk_k<<<B_*H_*16, 256, 0, stream>>>(qkvb, scores);
    softmax_k<<<B_*H_*T_, 256, 0, stream>>>(scores);
    pv_k<<<B_*H_*16, 256, 0, stream>>>(scores, qkvb, actA);
    gemm_bt<1,float,false><<<dim3(16,8), 256, 0, stream>>>(
        actA, pw_bf + (size_t)l*D_*D_, proj_b + l*D_, xb, xb, M_, D_, D_);
    ln_k<<<M_, 256, 0, stream>>>(xb, ln2_w + l*D_, ln2_b + l*D_, actA);
    gemm_bt<2,u16,false><<<dim3(16,32), 256, 0, stream>>>(
        actA, fw_bf + (size_t)l*4*D_*D_, fc_b + l*4*D_, nullptr, actB, M_, 4*D_, D_);
    gemm_bt<1,float,false><<<dim3(16,8), 256, 0, stream>>>(
        actB, fpw_bf + (size_t)l*D_*4*D_, fcp_b + l*D_, xb, xb, M_, D_, 4*D_);
  }

  ln_k<<<M_, 256, 0, stream>>>(xb, lnf_w, lnf_b, actA);
  float* logits = (float*)d_out;
  gemm_bt<0,float,true><<<dim3(16, (V_+127)/128), 256, 0, stream>>>(
      actA, wte_bf, nullptr, nullptr, logits, M_, V_, D_);
  loss_row_k<<<M_, 256, 0, stream>>>(logits, targets, rowloss);
  loss_reduce_k<<<1, 256, 0, stream>>>(rowloss, logits + (size_t)M_*V_);
}

// Round 2
// 3016.003 us; speedup vs baseline: 1.3090x; 1.2819x over previous
//
#include <hip/hip_runtime.h>
#include <hip/hip_bf16.h>
#include <math.h>

#define L_ 6
#define H_ 16
#define D_ 1024
#define V_ 50257
#define B_ 2
#define T_ 1024
#define M_ (B_*T_)

typedef unsigned short u16;
typedef __attribute__((ext_vector_type(8))) __bf16 bf16x8;
typedef __attribute__((ext_vector_type(8))) unsigned short u16x8;
typedef __attribute__((ext_vector_type(4))) float f32x4;

__device__ __forceinline__ u16 f2bf(float x){
  union { __hip_bfloat16 h; u16 u; } c;
  c.h = __float2bfloat16(x);
  return c.u;
}

__device__ __forceinline__ void gload_lds16(const void* g, void* l){
  __builtin_amdgcn_global_load_lds(
      (__attribute__((address_space(1))) void*)(const_cast<void*>(g)),
      (__attribute__((address_space(3))) void*)l, 16, 0, 0);
}

// ---------------- fp32 -> bf16 weight conversion ----------------
__global__ void cvt_bf16x4(const float4* __restrict__ in, ushort4* __restrict__ out, int n4){
  int i = blockIdx.x*256 + threadIdx.x;
  if (i < n4){
    float4 v = in[i];
    ushort4 o;
    o.x = f2bf(v.x); o.y = f2bf(v.y); o.z = f2bf(v.z); o.w = f2bf(v.w);
    out[i] = o;
  }
}

// ---------------- embedding ----------------
__global__ void embed_k(const int* __restrict__ idx, const float* __restrict__ wte,
                        const float* __restrict__ wpe, float* __restrict__ xb){
  int m = blockIdx.x;
  int t = m % T_;
  int tok = idx[m];
  const float* w = wte + (size_t)tok*D_;
  const float* p = wpe + (size_t)t*D_;
  float* o = xb + (size_t)m*D_;
  for (int d = threadIdx.x; d < D_; d += 256) o[d] = w[d] + p[d];
}

// ---------------- layernorm (fp32 in, bf16 out) ----------------
__global__ __launch_bounds__(256) void ln_k(const float* __restrict__ x, const float* __restrict__ w,
                     const float* __restrict__ b, u16* __restrict__ out){
  __shared__ float sm[8];
  int m = blockIdx.x, t = threadIdx.x;
  const float4* xr = (const float4*)(x + (size_t)m*D_);
  float4 v = xr[t];
  float s  = v.x+v.y+v.z+v.w;
  float ss = v.x*v.x+v.y*v.y+v.z*v.z+v.w*v.w;
  for (int o=32;o;o>>=1){ s += __shfl_down(s,o,64); ss += __shfl_down(ss,o,64); }
  if ((t&63)==0){ sm[t>>6]=s; sm[4+(t>>6)]=ss; }
  __syncthreads();
  s  = sm[0]+sm[1]+sm[2]+sm[3];
  ss = sm[4]+sm[5]+sm[6]+sm[7];
  float mean = s*(1.0f/D_);
  float var  = ss*(1.0f/D_) - mean*mean;
  float rstd = rsqrtf(var + 1e-5f);
  float4 wv = ((const float4*)w)[t];
  float4 bv = ((const float4*)b)[t];
  ushort4 o4;
  o4.x = f2bf((v.x-mean)*rstd*wv.x + bv.x);
  o4.y = f2bf((v.y-mean)*rstd*wv.y + bv.y);
  o4.z = f2bf((v.z-mean)*rstd*wv.z + bv.z);
  o4.w = f2bf((v.w-mean)*rstd*wv.w + bv.w);
  ((ushort4*)(out + (size_t)m*D_))[t] = o4;
}

// ---------------- GEMM: C[M,N] = A[M,K] * W[N,K]^T (+bias)(+resid)(gelu) ----------------
__device__ __forceinline__ void storeval(float* C, size_t i, float v){ C[i] = v; }
__device__ __forceinline__ void storeval(u16*   C, size_t i, float v){ C[i] = f2bf(v); }

template<int KIND, typename OUT_T, bool NB>
__global__ __launch_bounds__(256) void gemm_bt(const u16* __restrict__ A, const u16* __restrict__ W,
    const float* __restrict__ bias, const float* __restrict__ resid,
    OUT_T* __restrict__ C, int M, int N, int K)
{
  __shared__ u16 lA[128*64];
  __shared__ u16 lB[128*64];
  int t = threadIdx.x;
  int m0 = blockIdx.x*128, n0 = blockIdx.y*128;
  int w = t>>6, lane = t&63, quad = lane>>4, lm = lane&15;
  int wr = w>>1, wc = w&1;
  int arow = t>>3, aseg = t&7;
  f32x4 acc[4][4] = {};
  for (int k0 = 0; k0 < K; k0 += 64){
    __syncthreads();
    #pragma unroll
    for (int it=0; it<4; it++){
      gload_lds16(A + (size_t)(m0 + it*32 + arow)*K + k0 + aseg*8, &lA[it*2048 + t*8]);
      int br = n0 + it*32 + arow;
      if (NB) br = (br < N) ? br : (N-1);
      gload_lds16(W + (size_t)br*K + k0 + aseg*8, &lB[it*2048 + t*8]);
    }
    __syncthreads();
    #pragma unroll
    for (int kk=0; kk<64; kk+=32){
      bf16x8 af[4], bfr[4];
      #pragma unroll
      for (int i=0;i<4;i++) af[i]  = *(const bf16x8*)&lA[(wr*64+i*16+lm)*64 + kk + quad*8];
      #pragma unroll
      for (int j=0;j<4;j++) bfr[j] = *(const bf16x8*)&lB[(wc*64+j*16+lm)*64 + kk + quad*8];
      #pragma unroll
      for (int i=0;i<4;i++)
        #pragma unroll
        for (int j=0;j<4;j++)
          acc[i][j] = __builtin_amdgcn_mfma_f32_16x16x32_bf16(af[i], bfr[j], acc[i][j], 0,0,0);
    }
  }
  #pragma unroll
  for (int i=0;i<4;i++){
    int mb = m0 + wr*64 + i*16 + quad*4;
    #pragma unroll
    for (int j=0;j<4;j++){
      int n = n0 + wc*64 + j*16 + lm;
      if (NB && n >= N) continue;
      float bv = bias ? bias[n] : 0.0f;
      #pragma unroll
      for (int r=0;r<4;r++){
        float v = acc[i][j][r] + bv;
        int mm = mb + r;
        if (KIND==1) v += resid[(size_t)mm*N + n];
        if (KIND==2) v = 0.5f*v*(1.0f + erff(v*0.70710678118654752f));
        storeval(C, (size_t)mm*(size_t)N + n, v);
      }
    }
  }
}

// ---------------- attention helpers: swizzled 64x64 bf16 LDS tiles ----------------
// LDS layout: row-major [64][64] u16 (128 B rows). 16B chunk c of row r stored at
// chunk (c ^ (r&7)) — both ds_write (staging) and ds_read (fragments) apply the XOR,
// spreading the wave's 64 b128 accesses over all 8 chunk slots (bank floor).
__device__ __forceinline__ void stage64(u16* lds, const u16* g, size_t rowstride){
  int t = threadIdx.x;
  #pragma unroll
  for (int ch = t; ch < 512; ch += 256){
    int row = ch>>3, seg = ch&7;
    int sw = seg ^ (row & 7);
    *(u16x8*)&lds[row*64 + sw*8] = *(const u16x8*)(g + (size_t)row*rowstride + seg*8);
  }
}
__device__ __forceinline__ bf16x8 ldfrag(const u16* lds, int r, int c){
  return *(const bf16x8*)&lds[r*64 + ((c ^ (r&7))&7)*8];
}

// ---------------- attention: S = scale*Q K^T (causal tiles only), MFMA ----------------
__global__ __launch_bounds__(256) void qk_k(const u16* __restrict__ qkv, float* __restrict__ S){
  __shared__ u16 lQ[4096];
  __shared__ u16 lK[4096];
  int blk = blockIdx.x;
  int qt = blk & 15, bh = blk >> 4;
  int b = bh >> 4, h = bh & 15;
  int t = threadIdx.x, w = t>>6, lane = t&63, quad = lane>>4, lm = lane&15;
  const u16* qbase = qkv + (size_t)(b*T_ + qt*64)*3072 + h*64;
  const u16* kbase = qkv + (size_t)b*T_*3072 + 1024 + h*64;
  stage64(lQ, qbase, 3072);
  float* Srow = S + ((size_t)bh*T_ + qt*64)*T_;
  for (int kt=0; kt<=qt; kt++){
    __syncthreads();
    stage64(lK, kbase + (size_t)kt*64*3072, 3072);
    __syncthreads();
    f32x4 acc[4] = {};
    #pragma unroll
    for (int kk=0; kk<2; kk++){
      bf16x8 af = ldfrag(lQ, w*16+lm, kk*4+quad);
      #pragma unroll
      for (int j=0;j<4;j++){
        bf16x8 bf = ldfrag(lK, j*16+lm, kk*4+quad);
        acc[j] = __builtin_amdgcn_mfma_f32_16x16x32_bf16(af, bf, acc[j], 0,0,0);
      }
    }
    #pragma unroll
    for (int j=0;j<4;j++){
      #pragma unroll
      for (int r=0;r<4;r++){
        int qrow = w*16 + quad*4 + r;
        int q = qt*64 + qrow;
        int k = kt*64 + j*16 + lm;
        Srow[(size_t)qrow*T_ + k] = (k<=q) ? acc[j][r]*0.125f : -1e30f;
      }
    }
  }
}

// ---------------- V transpose: vt[bh][d][k] bf16 (makes PV B-operand K-major) --------
__global__ __launch_bounds__(256) void vt_k(const u16* __restrict__ qkv, u16* __restrict__ vt){
  __shared__ u16 lT[4096];   // [64 k][64 d], chunk-swizzled by (k>>3)
  int blk = blockIdx.x;
  int kt = blk & 15, bh = blk >> 4;
  int b = bh >> 4, h = bh & 15;
  int t = threadIdx.x;
  #pragma unroll
  for (int ch = t; ch < 512; ch += 256){
    int row = ch>>3, seg = ch&7;
    int sw = seg ^ (row>>3);
    const u16* src = qkv + (size_t)(b*T_ + kt*64 + row)*3072 + 2048 + h*64 + seg*8;
    *(u16x8*)&lT[row*64 + sw*8] = *(const u16x8*)src;
  }
  __syncthreads();
  #pragma unroll
  for (int ch = t; ch < 512; ch += 256){
    int d = ch>>3, sk = ch&7;
    u16x8 o;
    #pragma unroll
    for (int i=0;i<8;i++){
      int k = sk*8 + i;
      o[i] = lT[k*64 + ((((d>>3) ^ sk)&7)*8) + (d&7)];
    }
    *(u16x8*)(vt + (size_t)(bh*64 + d)*T_ + kt*64 + sk*8) = o;
  }
}

// ---------------- causal-prefix softmax over rows of S; P out in bf16 ----------------
__global__ __launch_bounds__(256) void softmax_k(const float* __restrict__ S, u16* __restrict__ P){
  __shared__ float sm[8];
  int row = blockIdx.x;
  int q = row & (T_-1);
  int len = ((q>>6)+1)*64;
  const float* p = S + (size_t)row*T_;
  u16* po = P + (size_t)row*T_;
  int t = threadIdx.x;
  float v[4];
  float mx = -1e30f;
  #pragma unroll
  for (int r=0;r<4;r++){
    int i = t + r*256;
    v[r] = (i<len) ? p[i] : -1e30f;
    mx = fmaxf(mx, v[r]);
  }
  for (int o=32;o;o>>=1) mx = fmaxf(mx, __shfl_down(mx,o,64));
  if ((t&63)==0) sm[t>>6]=mx;
  __syncthreads();
  mx = fmaxf(fmaxf(sm[0],sm[1]), fmaxf(sm[2],sm[3]));
  float s = 0.f;
  #pragma unroll
  for (int r=0;r<4;r++){
    int i = t + r*256;
    v[r] = (i<len) ? expf(v[r]-mx) : 0.f;
    s += v[r];
  }
  for (int o=32;o;o>>=1) s += __shfl_down(s,o,64);
  if ((t&63)==0) sm[4+(t>>6)]=s;
  __syncthreads();
  s = sm[4]+sm[5]+sm[6]+sm[7];
  float inv = 1.0f/s;
  #pragma unroll
  for (int r=0;r<4;r++){
    int i = t + r*256;
    if (i<len) po[i] = f2bf(v[r]*inv);
  }
}

// ---------------- y = P V via MFMA (bf16 out into activation buffer) ----------------
__global__ __launch_bounds__(256) void pv_k(const u16* __restrict__ P, const u16* __restrict__ vt,
                                            u16* __restrict__ out){
  __shared__ u16 lP[4096];
  __shared__ u16 lV[4096];
  int blk = blockIdx.x;
  int qt = blk & 15, bh = blk >> 4;
  int b = bh >> 4, h = bh & 15;
  int t = threadIdx.x, w = t>>6, lane = t&63, quad = lane>>4, lm = lane&15;
  const u16* pbase = P + ((size_t)bh*T_ + qt*64)*T_;
  const u16* vbase = vt + (size_t)bh*64*T_;
  f32x4 acc[4] = {};
  for (int kt=0; kt<=qt; kt++){
    __syncthreads();
    stage64(lP, pbase + kt*64, T_);
    stage64(lV, vbase + kt*64, T_);
    __syncthreads();
    #pragma unroll
    for (int kk=0; kk<2; kk++){
      bf16x8 af = ldfrag(lP, w*16+lm, kk*4+quad);
      #pragma unroll
      for (int j=0;j<4;j++){
        bf16x8 bf = ldfrag(lV, j*16+lm, kk*4+quad);
        acc[j] = __builtin_amdgcn_mfma_f32_16x16x32_bf16(af, bf, acc[j], 0,0,0);
      }
    }
  }
  size_t obase = (size_t)(b*T_ + qt*64)*D_ + h*64;
  #pragma unroll
  for (int j=0;j<4;j++){
    #pragma unroll
    for (int r=0;r<4;r++){
      int qrow = w*16 + quad*4 + r;
      out[obase + (size_t)qrow*D_ + j*16 + lm] = f2bf(acc[j][r]);
    }
  }
}

// ---------------- loss (single-pass online max/sum) ----------------
__global__ __launch_bounds__(256) void loss_row_k(const float* __restrict__ logits,
                                                  const int* __restrict__ targets,
                                                  float* __restrict__ rowloss){
  __shared__ float smx[4], ssm[4];
  int m = blockIdx.x, t = threadIdx.x;
  const float* p = logits + (size_t)m*V_;
  float mx = -1e30f, s = 0.f;
  for (int i=t;i<V_;i+=256){
    float v = p[i];
    if (v > mx){ s = s*expf(mx - v) + 1.0f; mx = v; }
    else        s += expf(v - mx);
  }
  for (int o=32;o;o>>=1){
    float omx = __shfl_down(mx,o,64);
    float os  = __shfl_down(s,o,64);
    float nm = fmaxf(mx, omx);
    s = s*expf(mx-nm) + os*expf(omx-nm);
    mx = nm;
  }
  if ((t&63)==0){ smx[t>>6]=mx; ssm[t>>6]=s; }
  __syncthreads();
  if (t==0){
    float gm = fmaxf(fmaxf(smx[0],smx[1]), fmaxf(smx[2],smx[3]));
    float gs = ssm[0]*expf(smx[0]-gm) + ssm[1]*expf(smx[1]-gm)
             + ssm[2]*expf(smx[2]-gm) + ssm[3]*expf(smx[3]-gm);
    rowloss[m] = logf(gs) + gm - p[targets[m]];
  }
}

__global__ void loss_reduce_k(const float* __restrict__ rowloss, float* __restrict__ out){
  __shared__ float sm[4];
  int t = threadIdx.x;
  float s = 0.f;
  for (int i=t;i<M_;i+=256) s += rowloss[i];
  for (int o=32;o;o>>=1) s += __shfl_down(s,o,64);
  if ((t&63)==0) sm[t>>6]=s;
  __syncthreads();
  if (t==0) out[0] = (sm[0]+sm[1]+sm[2]+sm[3])*(1.0f/M_);
}

// ---------------- launch ----------------
extern "C" void kernel_launch(void* const* d_in, const int* in_sizes, int n_in,
                              void* d_out, int out_size, void* d_ws, size_t ws_size,
                              hipStream_t stream) {
  const int*   idx     = (const int*)d_in[0];
  const int*   targets = (const int*)d_in[1];
  const float* wte     = (const float*)d_in[2];
  const float* wpe     = (const float*)d_in[3];
  const float* ln1_w   = (const float*)d_in[4];
  const float* ln1_b   = (const float*)d_in[5];
  const float* attn_w  = (const float*)d_in[6];
  const float* attn_b  = (const float*)d_in[7];
  const float* proj_w  = (const float*)d_in[8];
  const float* proj_b  = (const float*)d_in[9];
  const float* ln2_w   = (const float*)d_in[10];
  const float* ln2_b   = (const float*)d_in[11];
  const float* fc_w    = (const float*)d_in[12];
  const float* fc_b    = (const float*)d_in[13];
  const float* fcp_w   = (const float*)d_in[14];
  const float* fcp_b   = (const float*)d_in[15];
  const float* lnf_w   = (const float*)d_in[16];
  const float* lnf_b   = (const float*)d_in[17];

  char* ws = (char*)d_ws;
  size_t off = 0;
  auto alloc = [&](size_t bytes)->void*{ void* p = ws + off; off += (bytes + 255) & ~(size_t)255; return p; };
  u16*   wte_bf  = (u16*)  alloc((size_t)V_*D_*2);
  u16*   aw_bf   = (u16*)  alloc((size_t)L_*3*D_*D_*2);
  u16*   pw_bf   = (u16*)  alloc((size_t)L_*D_*D_*2);
  u16*   fw_bf   = (u16*)  alloc((size_t)L_*4*D_*D_*2);
  u16*   fpw_bf  = (u16*)  alloc((size_t)L_*D_*4*D_*2);
  float* xb      = (float*)alloc((size_t)M_*D_*4);
  u16*   actA    = (u16*)  alloc((size_t)M_*4*D_*2);
  u16*   actB    = (u16*)  alloc((size_t)M_*4*D_*2);
  u16*   qkv_bf  = (u16*)  alloc((size_t)M_*3*D_*2);
  u16*   vt_bf   = (u16*)  alloc((size_t)B_*H_*64*T_*2);
  float* scores  = (float*)alloc((size_t)B_*H_*T_*T_*4);
  u16*   pbf     = (u16*)  alloc((size_t)B_*H_*T_*T_*2);
  float* rowloss = (float*)alloc((size_t)M_*4);
  (void)ws_size; (void)in_sizes; (void)n_in; (void)out_size;

  auto cvt = [&](const float* in, u16* out, size_t n){
    int n4 = (int)(n/4);
    cvt_bf16x4<<<dim3((n4+255)/256), dim3(256), 0, stream>>>((const float4*)in, (ushort4*)out, n4);
  };
  cvt(wte,    wte_bf, (size_t)V_*D_);
  cvt(attn_w, aw_bf,  (size_t)L_*3*D_*D_);
  cvt(proj_w, pw_bf,  (size_t)L_*D_*D_);
  cvt(fc_w,   fw_bf,  (size_t)L_*4*D_*D_);
  cvt(fcp_w,  fpw_bf, (size_t)L_*D_*4*D_);

  embed_k<<<M_, 256, 0, stream>>>(idx, wte, wpe, xb);

  for (int l=0; l<L_; l++){
    ln_k<<<M_, 256, 0, stream>>>(xb, ln1_w + l*D_, ln1_b + l*D_, actA);
    gemm_bt<0,u16,false><<<dim3(16,24), 256, 0, stream>>>(
        actA, aw_bf + (size_t)l*3*D_*D_, attn_b + l*3*D_, nullptr, qkv_bf, M_, 3*D_, D_);
    vt_k<<<B_*H_*16, 256, 0, stream>>>(qkv_bf, vt_bf);
    qk_k<<<B_*H_*16, 256, 0, stream>>>(qkv_bf, scores);
    softmax_k<<<B_*H_*T_, 256, 0, stream>>>(scores, pbf);
    pv_k<<<B_*H_*16, 256, 0, stream>>>(pbf, vt_bf, actA);
    gemm_bt<1,float,false><<<dim3(16,8), 256, 0, stream>>>(
        actA, pw_bf + (size_t)l*D_*D_, proj_b + l*D_, xb, xb, M_, D_, D_);
    ln_k<<<M_, 256, 0, stream>>>(xb, ln2_w + l*D_, ln2_b + l*D_, actA);
    gemm_bt<2,u16,false><<<dim3(16,32), 256, 0, stream>>>(
        actA, fw_bf + (size_t)l*4*D_*D_, fc_b + l*4*D_, nullptr, actB, M_, 4*D_, D_);
    gemm_bt<1,float,false><<<dim3(16,8), 256, 0, stream>>>(
        actB, fpw_bf + (size_t)l*D_*4*D_, fcp_b + l*D_, xb, xb, M_, D_, 4*D_);
  }

  ln_k<<<M_, 256, 0, stream>>>(xb, lnf_w, lnf_b, actA);
  float* logits = (float*)d_out;
  gemm_bt<0,float,true><<<dim3(16, (V_+127)/128), 256, 0, stream>>>(
      actA, wte_bf, nullptr, nullptr, logits, M_, V_, D_);
  loss_row_k<<<M_, 256, 0, stream>>>(logits, targets, rowloss);
  loss_reduce_k<<<1, 256, 0, stream>>>(rowloss, logits + (size_t)M_*V_);
}

// Round 3
// 2800.569 us; speedup vs baseline: 1.4096x; 1.0769x over previous
//
#include <hip/hip_runtime.h>
#include <hip/hip_bf16.h>
#include <math.h>

#define L_ 6
#define H_ 16
#define D_ 1024
#define V_ 50257
#define B_ 2
#define T_ 1024
#define M_ (B_*T_)

typedef unsigned short u16;
typedef __attribute__((ext_vector_type(8))) __bf16 bf16x8;
typedef __attribute__((ext_vector_type(8))) unsigned short u16x8;
typedef __attribute__((ext_vector_type(4))) float f32x4;

__device__ __forceinline__ u16 f2bf(float x){
  union { __hip_bfloat16 h; u16 u; } c;
  c.h = __float2bfloat16(x);
  return c.u;
}

__device__ __forceinline__ void gload_lds16(const void* g, void* l){
  __builtin_amdgcn_global_load_lds(
      (__attribute__((address_space(1))) void*)(const_cast<void*>(g)),
      (__attribute__((address_space(3))) void*)l, 16, 0, 0);
}

// ---------------- fp32 -> bf16 weight conversion ----------------
__global__ void cvt_bf16x4(const float4* __restrict__ in, ushort4* __restrict__ out, int n4){
  int i = blockIdx.x*256 + threadIdx.x;
  if (i < n4){
    float4 v = in[i];
    ushort4 o;
    o.x = f2bf(v.x); o.y = f2bf(v.y); o.z = f2bf(v.z); o.w = f2bf(v.w);
    out[i] = o;
  }
}

// ---------------- embedding ----------------
__global__ void embed_k(const int* __restrict__ idx, const float* __restrict__ wte,
                        const float* __restrict__ wpe, float* __restrict__ xb){
  int m = blockIdx.x;
  int t = m % T_;
  int tok = idx[m];
  const float* w = wte + (size_t)tok*D_;
  const float* p = wpe + (size_t)t*D_;
  float* o = xb + (size_t)m*D_;
  for (int d = threadIdx.x; d < D_; d += 256) o[d] = w[d] + p[d];
}

// ---------------- layernorm (fp32 in, bf16 out) ----------------
__global__ __launch_bounds__(256) void ln_k(const float* __restrict__ x, const float* __restrict__ w,
                     const float* __restrict__ b, u16* __restrict__ out){
  __shared__ float sm[8];
  int m = blockIdx.x, t = threadIdx.x;
  const float4* xr = (const float4*)(x + (size_t)m*D_);
  float4 v = xr[t];
  float s  = v.x+v.y+v.z+v.w;
  float ss = v.x*v.x+v.y*v.y+v.z*v.z+v.w*v.w;
  for (int o=32;o;o>>=1){ s += __shfl_down(s,o,64); ss += __shfl_down(ss,o,64); }
  if ((t&63)==0){ sm[t>>6]=s; sm[4+(t>>6)]=ss; }
  __syncthreads();
  s  = sm[0]+sm[1]+sm[2]+sm[3];
  ss = sm[4]+sm[5]+sm[6]+sm[7];
  float mean = s*(1.0f/D_);
  float var  = ss*(1.0f/D_) - mean*mean;
  float rstd = rsqrtf(var + 1e-5f);
  float4 wv = ((const float4*)w)[t];
  float4 bv = ((const float4*)b)[t];
  ushort4 o4;
  o4.x = f2bf((v.x-mean)*rstd*wv.x + bv.x);
  o4.y = f2bf((v.y-mean)*rstd*wv.y + bv.y);
  o4.z = f2bf((v.z-mean)*rstd*wv.z + bv.z);
  o4.w = f2bf((v.w-mean)*rstd*wv.w + bv.w);
  ((ushort4*)(out + (size_t)m*D_))[t] = o4;
}

// ---------------- GEMM: C[M,N] = A[M,K] * W[N,K]^T (+bias)(+resid)(gelu)(+loss stats) ----
// KIND: 0=plain, 1=+resid, 2=gelu, 3=plain + per-block online (max,expsum) row partials
__device__ __forceinline__ void storeval(float* C, size_t i, float v){ C[i] = v; }
__device__ __forceinline__ void storeval(u16*   C, size_t i, float v){ C[i] = f2bf(v); }

template<int KIND, typename OUT_T, bool NB>
__global__ __launch_bounds__(256) void gemm_bt(const u16* __restrict__ A, const u16* __restrict__ W,
    const float* __restrict__ bias, const float* __restrict__ resid,
    OUT_T* __restrict__ C, float2* __restrict__ stats, int M, int N, int K)
{
  __shared__ u16 lA[128*64];
  __shared__ u16 lB[128*64];
  __shared__ float2 lstat[128][2];
  int t = threadIdx.x;
  int m0 = blockIdx.x*128, n0 = blockIdx.y*128;
  int w = t>>6, lane = t&63, quad = lane>>4, lm = lane&15;
  int wr = w>>1, wc = w&1;
  int arow = t>>3, aseg = t&7;
  f32x4 acc[4][4] = {};
  for (int k0 = 0; k0 < K; k0 += 64){
    __syncthreads();
    #pragma unroll
    for (int it=0; it<4; it++){
      gload_lds16(A + (size_t)(m0 + it*32 + arow)*K + k0 + aseg*8, &lA[it*2048 + t*8]);
      int br = n0 + it*32 + arow;
      if (NB) br = (br < N) ? br : (N-1);
      gload_lds16(W + (size_t)br*K + k0 + aseg*8, &lB[it*2048 + t*8]);
    }
    __syncthreads();
    #pragma unroll
    for (int kk=0; kk<64; kk+=32){
      bf16x8 af[4], bfr[4];
      #pragma unroll
      for (int i=0;i<4;i++) af[i]  = *(const bf16x8*)&lA[(wr*64+i*16+lm)*64 + kk + quad*8];
      #pragma unroll
      for (int j=0;j<4;j++) bfr[j] = *(const bf16x8*)&lB[(wc*64+j*16+lm)*64 + kk + quad*8];
      #pragma unroll
      for (int i=0;i<4;i++)
        #pragma unroll
        for (int j=0;j<4;j++)
          acc[i][j] = __builtin_amdgcn_mfma_f32_16x16x32_bf16(af[i], bfr[j], acc[i][j], 0,0,0);
    }
  }
  #pragma unroll
  for (int i=0;i<4;i++){
    int mb = m0 + wr*64 + i*16 + quad*4;
    float vv[4][4];
    #pragma unroll
    for (int j=0;j<4;j++){
      int n = n0 + wc*64 + j*16 + lm;
      bool valid = !(NB && n >= N);
      float bv = (bias && valid) ? bias[n] : 0.0f;
      #pragma unroll
      for (int r=0;r<4;r++){
        float v = acc[i][j][r] + bv;
        int mm = mb + r;
        if (KIND==1) v += resid[(size_t)mm*N + n];
        if (KIND==2) v = 0.5f*v*(1.0f + erff(v*0.70710678118654752f));
        if (valid) storeval(C, (size_t)mm*(size_t)N + n, v);
        vv[j][r] = valid ? v : -1e30f;
      }
    }
    if (KIND==3){
      #pragma unroll
      for (int r=0;r<4;r++){
        float mx = fmaxf(fmaxf(vv[0][r],vv[1][r]), fmaxf(vv[2][r],vv[3][r]));
        #pragma unroll
        for (int o=1;o<16;o<<=1) mx = fmaxf(mx, __shfl_xor(mx,o,16));
        float ps = expf(vv[0][r]-mx)+expf(vv[1][r]-mx)+expf(vv[2][r]-mx)+expf(vv[3][r]-mx);
        #pragma unroll
        for (int o=1;o<16;o<<=1) ps += __shfl_xor(ps,o,16);
        if (lm==0) lstat[wr*64 + i*16 + quad*4 + r][wc] = make_float2(mx, ps);
      }
    }
  }
  if (KIND==3){
    __syncthreads();
    if (t < 128){
      float2 a = lstat[t][0], c2 = lstat[t][1];
      float mm2 = fmaxf(a.x, c2.x);
      float ss2 = a.y*expf(a.x-mm2) + c2.y*expf(c2.x-mm2);
      stats[(size_t)(m0 + t)*gridDim.y + blockIdx.y] = make_float2(mm2, ss2);
    }
  }
}

// ---------------- attention helpers: swizzled 64x64 bf16 LDS tiles ----------------
__device__ __forceinline__ void stage64(u16* lds, const u16* g, size_t rowstride){
  int t = threadIdx.x;
  #pragma unroll
  for (int ch = t; ch < 512; ch += 256){
    int row = ch>>3, seg = ch&7;
    int sw = seg ^ (row & 7);
    *(u16x8*)&lds[row*64 + sw*8] = *(const u16x8*)(g + (size_t)row*rowstride + seg*8);
  }
}
__device__ __forceinline__ bf16x8 ldfrag(const u16* lds, int r, int c){
  return *(const bf16x8*)&lds[r*64 + ((c ^ (r&7))&7)*8];
}

// ---------------- V transpose: vt[bh][d][k] bf16 (makes PV B-operand K-major) --------
__global__ __launch_bounds__(256) void vt_k(const u16* __restrict__ qkv, u16* __restrict__ vt){
  __shared__ u16 lT[4096];   // [64 k][64 d], chunk-swizzled by (k>>3)
  int blk = blockIdx.x;
  int kt = blk & 15, bh = blk >> 4;
  int b = bh >> 4, h = bh & 15;
  int t = threadIdx.x;
  #pragma unroll
  for (int ch = t; ch < 512; ch += 256){
    int row = ch>>3, seg = ch&7;
    int sw = seg ^ (row>>3);
    const u16* src = qkv + (size_t)(b*T_ + kt*64 + row)*3072 + 2048 + h*64 + seg*8;
    *(u16x8*)&lT[row*64 + sw*8] = *(const u16x8*)src;
  }
  __syncthreads();
  #pragma unroll
  for (int ch = t; ch < 512; ch += 256){
    int d = ch>>3, sk = ch&7;
    u16x8 o;
    #pragma unroll
    for (int i=0;i<8;i++){
      int k = sk*8 + i;
      o[i] = lT[k*64 + ((((d>>3) ^ sk)&7)*8) + (d&7)];
    }
    *(u16x8*)(vt + (size_t)(bh*64 + d)*T_ + kt*64 + sk*8) = o;
  }
}

// ---------------- fused flash attention: QK^T -> online softmax -> PV ----------------
// One block per (bh, q-tile of 64). Each of 4 waves owns 16 q-rows.
// S/P/O live in registers; P bounced through LDS (bf16, swizzled) to become the
// PV A-operand. m/l tracked per lane-row (rows quad*4+r are lane-local in C-layout).
__global__ __launch_bounds__(256) void attn_k(const u16* __restrict__ qkv, const u16* __restrict__ vt,
                                              u16* __restrict__ out){
  __shared__ u16 lQ[4096], lK[4096], lV[4096], lP[4096];
  int blk = blockIdx.x;
  int qt = blk & 15, bh = blk >> 4;
  int b = bh >> 4, h = bh & 15;
  int t = threadIdx.x, w = t>>6, lane = t&63, quad = lane>>4, lm = lane&15;
  const u16* qbase = qkv + (size_t)(b*T_ + qt*64)*3072 + h*64;
  const u16* kbase = qkv + (size_t)b*T_*3072 + 1024 + h*64;
  const u16* vbase = vt + (size_t)bh*64*T_;
  stage64(lQ, qbase, 3072);
  f32x4 O[4] = {};
  float m[4], l[4];
  #pragma unroll
  for (int r=0;r<4;r++){ m[r] = -1e30f; l[r] = 0.f; }
  for (int kt=0; kt<=qt; kt++){
    __syncthreads();   // prior iter's lK/lV/lP reads done
    stage64(lK, kbase + (size_t)kt*64*3072, 3072);
    stage64(lV, vbase + kt*64, T_);
    __syncthreads();
    f32x4 s[4] = {};
    __builtin_amdgcn_s_setprio(1);
    #pragma unroll
    for (int kk=0; kk<2; kk++){
      bf16x8 af = ldfrag(lQ, w*16+lm, kk*4+quad);
      #pragma unroll
      for (int j=0;j<4;j++)
        s[j] = __builtin_amdgcn_mfma_f32_16x16x32_bf16(af, ldfrag(lK, j*16+lm, kk*4+quad), s[j], 0,0,0);
    }
    __builtin_amdgcn_s_setprio(0);
    int qrow = qt*64 + w*16 + quad*4;
    #pragma unroll
    for (int r=0;r<4;r++){
      float mx = -1e30f;
      #pragma unroll
      for (int j=0;j<4;j++){
        int k = kt*64 + j*16 + lm;
        float v = (k <= qrow + r) ? s[j][r]*0.125f : -1e30f;
        s[j][r] = v;
        mx = fmaxf(mx, v);
      }
      #pragma unroll
      for (int o=1;o<16;o<<=1) mx = fmaxf(mx, __shfl_xor(mx, o, 16));
      float mn = fmaxf(m[r], mx);
      float sc = expf(m[r] - mn);
      float ps = 0.f;
      #pragma unroll
      for (int j=0;j<4;j++){
        float p = expf(s[j][r] - mn);
        s[j][r] = p; ps += p;
      }
      #pragma unroll
      for (int o=1;o<16;o<<=1) ps += __shfl_xor(ps, o, 16);
      l[r] = l[r]*sc + ps; m[r] = mn;
      O[0][r] *= sc; O[1][r] *= sc; O[2][r] *= sc; O[3][r] *= sc;
    }
    // P -> LDS (bf16, same swizzle convention as stage64/ldfrag)
    #pragma unroll
    for (int j=0;j<4;j++){
      int ch = j*2 + (lm>>3);
      #pragma unroll
      for (int r=0;r<4;r++){
        int row = w*16 + quad*4 + r;
        lP[row*64 + ((ch ^ (row&7))&7)*8 + (lm&7)] = f2bf(s[j][r]);
      }
    }
    __syncthreads();
    __builtin_amdgcn_s_setprio(1);
    #pragma unroll
    for (int kk=0; kk<2; kk++){
      bf16x8 pa = ldfrag(lP, w*16+lm, kk*4+quad);
      #pragma unroll
      for (int j=0;j<4;j++)
        O[j] = __builtin_amdgcn_mfma_f32_16x16x32_bf16(pa, ldfrag(lV, j*16+lm, kk*4+quad), O[j], 0,0,0);
    }
    __builtin_amdgcn_s_setprio(0);
  }
  size_t obase = (size_t)(b*T_ + qt*64)*D_ + h*64;
  #pragma unroll
  for (int r=0;r<4;r++){
    float inv = 1.0f / l[r];
    #pragma unroll
    for (int j=0;j<4;j++)
      out[obase + (size_t)(w*16+quad*4+r)*D_ + j*16 + lm] = f2bf(O[j][r]*inv);
  }
}

// ---------------- loss from per-block partials (reads 6.4 MB, not 412 MB) ------------
__global__ __launch_bounds__(256) void loss_row2_k(const float2* __restrict__ stats, int nb,
                                                   const float* __restrict__ logits,
                                                   const int* __restrict__ targets,
                                                   float* __restrict__ rowloss){
  __shared__ float smx[4], ssm[4];
  int mrow = blockIdx.x, t = threadIdx.x;
  const float2* p = stats + (size_t)mrow*nb;
  float mx = -1e30f, s = 0.f;
  for (int i=t;i<nb;i+=256){
    float2 v = p[i];
    float nm = fmaxf(mx, v.x);
    s = s*expf(mx-nm) + v.y*expf(v.x-nm);
    mx = nm;
  }
  for (int o=32;o;o>>=1){
    float omx = __shfl_down(mx,o,64);
    float os  = __shfl_down(s,o,64);
    float nm = fmaxf(mx, omx);
    s = s*expf(mx-nm) + os*expf(omx-nm);
    mx = nm;
  }
  if ((t&63)==0){ smx[t>>6]=mx; ssm[t>>6]=s; }
  __syncthreads();
  if (t==0){
    float gm = fmaxf(fmaxf(smx[0],smx[1]), fmaxf(smx[2],smx[3]));
    float gs = ssm[0]*expf(smx[0]-gm) + ssm[1]*expf(smx[1]-gm)
             + ssm[2]*expf(smx[2]-gm) + ssm[3]*expf(smx[3]-gm);
    rowloss[mrow] = logf(gs) + gm - logits[(size_t)mrow*V_ + targets[mrow]];
  }
}

__global__ void loss_reduce_k(const float* __restrict__ rowloss, float* __restrict__ out){
  __shared__ float sm[4];
  int t = threadIdx.x;
  float s = 0.f;
  for (int i=t;i<M_;i+=256) s += rowloss[i];
  for (int o=32;o;o>>=1) s += __shfl_down(s,o,64);
  if ((t&63)==0) sm[t>>6]=s;
  __syncthreads();
  if (t==0) out[0] = (sm[0]+sm[1]+sm[2]+sm[3])*(1.0f/M_);
}

// ---------------- launch ----------------
extern "C" void kernel_launch(void* const* d_in, const int* in_sizes, int n_in,
                              void* d_out, int out_size, void* d_ws, size_t ws_size,
                              hipStream_t stream) {
  const int*   idx     = (const int*)d_in[0];
  const int*   targets = (const int*)d_in[1];
  const float* wte     = (const float*)d_in[2];
  const float* wpe     = (const float*)d_in[3];
  const float* ln1_w   = (const float*)d_in[4];
  const float* ln1_b   = (const float*)d_in[5];
  const float* attn_w  = (const float*)d_in[6];
  const float* attn_b  = (const float*)d_in[7];
  const float* proj_w  = (const float*)d_in[8];
  const float* proj_b  = (const float*)d_in[9];
  const float* ln2_w   = (const float*)d_in[10];
  const float* ln2_b   = (const float*)d_in[11];
  const float* fc_w    = (const float*)d_in[12];
  const float* fc_b    = (const float*)d_in[13];
  const float* fcp_w   = (const float*)d_in[14];
  const float* fcp_b   = (const float*)d_in[15];
  const float* lnf_w   = (const float*)d_in[16];
  const float* lnf_b   = (const float*)d_in[17];

  const int NBY = (V_+127)/128;  // 393 lm-head N-blocks

  char* ws = (char*)d_ws;
  size_t off = 0;
  auto alloc = [&](size_t bytes)->void*{ void* p = ws + off; off += (bytes + 255) & ~(size_t)255; return p; };
  u16*   wte_bf  = (u16*)  alloc((size_t)V_*D_*2);
  u16*   aw_bf   = (u16*)  alloc((size_t)L_*3*D_*D_*2);
  u16*   pw_bf   = (u16*)  alloc((size_t)L_*D_*D_*2);
  u16*   fw_bf   = (u16*)  alloc((size_t)L_*4*D_*D_*2);
  u16*   fpw_bf  = (u16*)  alloc((size_t)L_*D_*4*D_*2);
  float* xb      = (float*)alloc((size_t)M_*D_*4);
  u16*   actA    = (u16*)  alloc((size_t)M_*4*D_*2);
  u16*   actB    = (u16*)  alloc((size_t)M_*4*D_*2);
  u16*   qkv_bf  = (u16*)  alloc((size_t)M_*3*D_*2);
  u16*   vt_bf   = (u16*)  alloc((size_t)B_*H_*64*T_*2);
  float2* stats  = (float2*)alloc((size_t)M_*NBY*8);
  float* rowloss = (float*)alloc((size_t)M_*4);
  (void)ws_size; (void)in_sizes; (void)n_in; (void)out_size;

  auto cvt = [&](const float* in, u16* out, size_t n){
    int n4 = (int)(n/4);
    cvt_bf16x4<<<dim3((n4+255)/256), dim3(256), 0, stream>>>((const float4*)in, (ushort4*)out, n4);
  };
  cvt(wte,    wte_bf, (size_t)V_*D_);
  cvt(attn_w, aw_bf,  (size_t)L_*3*D_*D_);
  cvt(proj_w, pw_bf,  (size_t)L_*D_*D_);
  cvt(fc_w,   fw_bf,  (size_t)L_*4*D_*D_);
  cvt(fcp_w,  fpw_bf, (size_t)L_*D_*4*D_);

  embed_k<<<M_, 256, 0, stream>>>(idx, wte, wpe, xb);

  for (int l=0; l<L_; l++){
    ln_k<<<M_, 256, 0, stream>>>(xb, ln1_w + l*D_, ln1_b + l*D_, actA);
    gemm_bt<0,u16,false><<<dim3(16,24), 256, 0, stream>>>(
        actA, aw_bf + (size_t)l*3*D_*D_, attn_b + l*3*D_, nullptr, qkv_bf, nullptr, M_, 3*D_, D_);
    vt_k<<<B_*H_*16, 256, 0, stream>>>(qkv_bf, vt_bf);
    attn_k<<<B_*H_*16, 256, 0, stream>>>(qkv_bf, vt_bf, actA);
    gemm_bt<1,float,false><<<dim3(16,8), 256, 0, stream>>>(
        actA, pw_bf + (size_t)l*D_*D_, proj_b + l*D_, xb, xb, nullptr, M_, D_, D_);
    ln_k<<<M_, 256, 0, stream>>>(xb, ln2_w + l*D_, ln2_b + l*D_, actA);
    gemm_bt<2,u16,false><<<dim3(16,32), 256, 0, stream>>>(
        actA, fw_bf + (size_t)l*4*D_*D_, fc_b + l*4*D_, nullptr, actB, nullptr, M_, 4*D_, D_);
    gemm_bt<1,float,false><<<dim3(16,8), 256, 0, stream>>>(
        actB, fpw_bf + (size_t)l*D_*4*D_, fcp_b + l*D_, xb, xb, nullptr, M_, D_, 4*D_);
  }

  ln_k<<<M_, 256, 0, stream>>>(xb, lnf_w, lnf_b, actA);
  float* logits = (float*)d_out;
  gemm_bt<3,float,true><<<dim3(16, NBY), 256, 0, stream>>>(
      actA, wte_bf, nullptr, nullptr, logits, stats, M_, V_, D_);
  loss_row2_k<<<M_, 256, 0, stream>>>(stats, NBY, logits, targets, rowloss);
  loss_reduce_k<<<1, 256, 0, stream>>>(rowloss, logits + (size_t)M_*V_);
}

// Round 4
// 2529.071 us; speedup vs baseline: 1.5610x; 1.1074x over previous
//
#include <hip/hip_runtime.h>
#include <hip/hip_bf16.h>
#include <math.h>

#define L_ 6
#define H_ 16
#define D_ 1024
#define V_ 50257
#define B_ 2
#define T_ 1024
#define M_ (B_*T_)

typedef unsigned short u16;
typedef __attribute__((ext_vector_type(8))) __bf16 bf16x8;
typedef __attribute__((ext_vector_type(8))) unsigned short u16x8;
typedef __attribute__((ext_vector_type(4))) float f32x4;

__device__ __forceinline__ u16 f2bf(float x){
  union { __hip_bfloat16 h; u16 u; } c;
  c.h = __float2bfloat16(x);
  return c.u;
}

__device__ __forceinline__ void gload_lds16(const void* g, void* l){
  __builtin_amdgcn_global_load_lds(
      (__attribute__((address_space(1))) void*)(const_cast<void*>(g)),
      (__attribute__((address_space(3))) void*)l, 16, 0, 0);
}

// ---------------- fp32 -> bf16 weight conversion ----------------
__global__ void cvt_bf16x4(const float4* __restrict__ in, ushort4* __restrict__ out, int n4){
  int i = blockIdx.x*256 + threadIdx.x;
  if (i < n4){
    float4 v = in[i];
    ushort4 o;
    o.x = f2bf(v.x); o.y = f2bf(v.y); o.z = f2bf(v.z); o.w = f2bf(v.w);
    out[i] = o;
  }
}

// ---------------- embedding ----------------
__global__ __launch_bounds__(256) void embed_k(const int* __restrict__ idx, const float* __restrict__ wte,
                        const float* __restrict__ wpe, float* __restrict__ xb){
  int m = blockIdx.x;
  int t = m % T_;
  int tok = idx[m];
  const float4* w = (const float4*)(wte + (size_t)tok*D_);
  const float4* p = (const float4*)(wpe + (size_t)t*D_);
  float4* o = (float4*)(xb + (size_t)m*D_);
  int d = threadIdx.x;
  float4 a = w[d], b = p[d];
  o[d] = make_float4(a.x+b.x, a.y+b.y, a.z+b.z, a.w+b.w);
}

// ---------------- layernorm (fp32 in, bf16 out) ----------------
__global__ __launch_bounds__(256) void ln_k(const float* __restrict__ x, const float* __restrict__ w,
                     const float* __restrict__ b, u16* __restrict__ out){
  __shared__ float sm[8];
  int m = blockIdx.x, t = threadIdx.x;
  const float4* xr = (const float4*)(x + (size_t)m*D_);
  float4 v = xr[t];
  float s  = v.x+v.y+v.z+v.w;
  float ss = v.x*v.x+v.y*v.y+v.z*v.z+v.w*v.w;
  for (int o=32;o;o>>=1){ s += __shfl_down(s,o,64); ss += __shfl_down(ss,o,64); }
  if ((t&63)==0){ sm[t>>6]=s; sm[4+(t>>6)]=ss; }
  __syncthreads();
  s  = sm[0]+sm[1]+sm[2]+sm[3];
  ss = sm[4]+sm[5]+sm[6]+sm[7];
  float mean = s*(1.0f/D_);
  float var  = ss*(1.0f/D_) - mean*mean;
  float rstd = rsqrtf(var + 1e-5f);
  float4 wv = ((const float4*)w)[t];
  float4 bv = ((const float4*)b)[t];
  ushort4 o4;
  o4.x = f2bf((v.x-mean)*rstd*wv.x + bv.x);
  o4.y = f2bf((v.y-mean)*rstd*wv.y + bv.y);
  o4.z = f2bf((v.z-mean)*rstd*wv.z + bv.z);
  o4.w = f2bf((v.w-mean)*rstd*wv.w + bv.w);
  ((ushort4*)(out + (size_t)m*D_))[t] = o4;
}

// ---------------- GEMM: C[M,N] = A[M,K] * W[N,K]^T -------------------------------
// KIND: 0=plain store, 1=+resid store, 2=gelu store,
//       3=plain store + per-block expsum row partials (max-free; logits bounded ~|21|),
//       4=split-K atomicAdd accumulate into C (C pre-holds residual; bias from z==0).
// lstat for KIND==3 is OVERLAID on lA (dead after K-loop) so LDS stays 32768 (5 blk/CU).
// KIND==3 reuses acc[][] to hold exp values -> no extra VGPR (peak set by K-loop).
__device__ __forceinline__ void storeval(float* C, size_t i, float v){ C[i] = v; }
__device__ __forceinline__ void storeval(u16*   C, size_t i, float v){ C[i] = f2bf(v); }

template<int KIND, typename OUT_T, bool NB>
__global__ __launch_bounds__(256) void gemm_bt(const u16* __restrict__ A, const u16* __restrict__ W,
    const float* __restrict__ bias, const float* __restrict__ resid,
    OUT_T* __restrict__ C, float* __restrict__ stats, int M, int N, int K)
{
  __shared__ u16 lA[128*64];
  __shared__ u16 lB[128*64];
  int t = threadIdx.x;
  int m0 = blockIdx.x*128, n0 = blockIdx.y*128;
  int w = t>>6, lane = t&63, quad = lane>>4, lm = lane&15;
  int wr = w>>1, wc = w&1;
  int arow = t>>3, aseg = t&7;
  int kbeg = 0, kend = K;
  if (KIND==4){
    int ks = K / gridDim.z;
    kbeg = blockIdx.z * ks; kend = kbeg + ks;
  }
  f32x4 acc[4][4] = {};
  for (int k0 = kbeg; k0 < kend; k0 += 64){
    __syncthreads();
    #pragma unroll
    for (int it=0; it<4; it++){
      gload_lds16(A + (size_t)(m0 + it*32 + arow)*K + k0 + aseg*8, &lA[it*2048 + t*8]);
      int br = n0 + it*32 + arow;
      if (NB) br = (br < N) ? br : (N-1);
      gload_lds16(W + (size_t)br*K + k0 + aseg*8, &lB[it*2048 + t*8]);
    }
    __syncthreads();
    #pragma unroll
    for (int kk=0; kk<64; kk+=32){
      bf16x8 af[4], bfr[4];
      #pragma unroll
      for (int i=0;i<4;i++) af[i]  = *(const bf16x8*)&lA[(wr*64+i*16+lm)*64 + kk + quad*8];
      #pragma unroll
      for (int j=0;j<4;j++) bfr[j] = *(const bf16x8*)&lB[(wc*64+j*16+lm)*64 + kk + quad*8];
      #pragma unroll
      for (int i=0;i<4;i++)
        #pragma unroll
        for (int j=0;j<4;j++)
          acc[i][j] = __builtin_amdgcn_mfma_f32_16x16x32_bf16(af[i], bfr[j], acc[i][j], 0,0,0);
    }
  }
  #pragma unroll
  for (int i=0;i<4;i++){
    int mb = m0 + wr*64 + i*16 + quad*4;
    #pragma unroll
    for (int j=0;j<4;j++){
      int n = n0 + wc*64 + j*16 + lm;
      bool valid = !(NB && n >= N);
      float bv = 0.0f;
      if (bias && valid){ if (KIND!=4 || blockIdx.z==0) bv = bias[n]; }
      #pragma unroll
      for (int r=0;r<4;r++){
        float v = acc[i][j][r] + bv;
        int mm = mb + r;
        size_t cix = (size_t)mm*(size_t)N + n;
        if constexpr (KIND==1) v += resid[cix];
        if constexpr (KIND==2) v = 0.5f*v*(1.0f + erff(v*0.70710678118654752f));
        if constexpr (KIND==4){
          if (valid) atomicAdd((float*)&C[cix], v);
        } else {
          if (valid) storeval(C, cix, v);
        }
        if constexpr (KIND==3) acc[i][j][r] = valid ? expf(v) : 0.0f;
      }
    }
  }
  if constexpr (KIND==3){
    __syncthreads();                 // all waves done reading lA/lB
    float* lsum = (float*)lA;        // overlay: [128 rows][2 wc]
    #pragma unroll
    for (int i=0;i<4;i++)
      #pragma unroll
      for (int r=0;r<4;r++){
        float ps = acc[i][0][r]+acc[i][1][r]+acc[i][2][r]+acc[i][3][r];
        #pragma unroll
        for (int o=1;o<16;o<<=1) ps += __shfl_xor(ps, o, 16);
        if (lm==0) lsum[(wr*64 + i*16 + quad*4 + r)*2 + wc] = ps;
      }
    __syncthreads();
    if (t < 128) stats[(size_t)(m0+t)*gridDim.y + blockIdx.y] = lsum[t*2] + lsum[t*2+1];
  }
}

// ---------------- attention helpers: swizzled 64x64 bf16 LDS tiles ----------------
__device__ __forceinline__ void stage64(u16* lds, const u16* g, size_t rowstride){
  int t = threadIdx.x;
  #pragma unroll
  for (int ch = t; ch < 512; ch += 256){
    int row = ch>>3, seg = ch&7;
    int sw = seg ^ (row & 7);
    *(u16x8*)&lds[row*64 + sw*8] = *(const u16x8*)(g + (size_t)row*rowstride + seg*8);
  }
}
__device__ __forceinline__ bf16x8 ldfrag(const u16* lds, int r, int c){
  return *(const bf16x8*)&lds[r*64 + ((c ^ (r&7))&7)*8];
}

// ---------------- V transpose: vt[bh][d][k] bf16 (makes PV B-operand K-major) --------
__global__ __launch_bounds__(256) void vt_k(const u16* __restrict__ qkv, u16* __restrict__ vt){
  __shared__ u16 lT[4096];   // [64 k][64 d], chunk-swizzled by (k>>3)
  int blk = blockIdx.x;
  int kt = blk & 15, bh = blk >> 4;
  int b = bh >> 4, h = bh & 15;
  int t = threadIdx.x;
  #pragma unroll
  for (int ch = t; ch < 512; ch += 256){
    int row = ch>>3, seg = ch&7;
    int sw = seg ^ (row>>3);
    const u16* src = qkv + (size_t)(b*T_ + kt*64 + row)*3072 + 2048 + h*64 + seg*8;
    *(u16x8*)&lT[row*64 + sw*8] = *(const u16x8*)src;
  }
  __syncthreads();
  #pragma unroll
  for (int ch = t; ch < 512; ch += 256){
    int d = ch>>3, sk = ch&7;
    u16x8 o;
    #pragma unroll
    for (int i=0;i<8;i++){
      int k = sk*8 + i;
      o[i] = lT[k*64 + ((((d>>3) ^ sk)&7)*8) + (d&7)];
    }
    *(u16x8*)(vt + (size_t)(bh*64 + d)*T_ + kt*64 + sk*8) = o;
  }
}

// ---------------- fused flash attention: QK^T -> online softmax -> PV ----------------
__global__ __launch_bounds__(256) void attn_k(const u16* __restrict__ qkv, const u16* __restrict__ vt,
                                              u16* __restrict__ out){
  __shared__ u16 lQ[4096], lK[4096], lV[4096], lP[4096];
  int blk = blockIdx.x;
  int qt = blk & 15, bh = blk >> 4;
  int b = bh >> 4, h = bh & 15;
  int t = threadIdx.x, w = t>>6, lane = t&63, quad = lane>>4, lm = lane&15;
  const u16* qbase = qkv + (size_t)(b*T_ + qt*64)*3072 + h*64;
  const u16* kbase = qkv + (size_t)b*T_*3072 + 1024 + h*64;
  const u16* vbase = vt + (size_t)bh*64*T_;
  stage64(lQ, qbase, 3072);
  f32x4 O[4] = {};
  float m[4], l[4];
  #pragma unroll
  for (int r=0;r<4;r++){ m[r] = -1e30f; l[r] = 0.f; }
  for (int kt=0; kt<=qt; kt++){
    __syncthreads();   // prior iter's lK/lV/lP reads done
    stage64(lK, kbase + (size_t)kt*64*3072, 3072);
    stage64(lV, vbase + kt*64, T_);
    __syncthreads();
    f32x4 s[4] = {};
    __builtin_amdgcn_s_setprio(1);
    #pragma unroll
    for (int kk=0; kk<2; kk++){
      bf16x8 af = ldfrag(lQ, w*16+lm, kk*4+quad);
      #pragma unroll
      for (int j=0;j<4;j++)
        s[j] = __builtin_amdgcn_mfma_f32_16x16x32_bf16(af, ldfrag(lK, j*16+lm, kk*4+quad), s[j], 0,0,0);
    }
    __builtin_amdgcn_s_setprio(0);
    int qrow = qt*64 + w*16 + quad*4;
    #pragma unroll
    for (int r=0;r<4;r++){
      float mx = -1e30f;
      #pragma unroll
      for (int j=0;j<4;j++){
        int k = kt*64 + j*16 + lm;
        float v = (k <= qrow + r) ? s[j][r]*0.125f : -1e30f;
        s[j][r] = v;
        mx = fmaxf(mx, v);
      }
      #pragma unroll
      for (int o=1;o<16;o<<=1) mx = fmaxf(mx, __shfl_xor(mx, o, 16));
      float mn = fmaxf(m[r], mx);
      float sc = expf(m[r] - mn);
      float ps = 0.f;
      #pragma unroll
      for (int j=0;j<4;j++){
        float p = expf(s[j][r] - mn);
        s[j][r] = p; ps += p;
      }
      #pragma unroll
      for (int o=1;o<16;o<<=1) ps += __shfl_xor(ps, o, 16);
      l[r] = l[r]*sc + ps; m[r] = mn;
      O[0][r] *= sc; O[1][r] *= sc; O[2][r] *= sc; O[3][r] *= sc;
    }
    // P -> LDS (bf16, same swizzle convention as stage64/ldfrag)
    #pragma unroll
    for (int j=0;j<4;j++){
      int ch = j*2 + (lm>>3);
      #pragma unroll
      for (int r=0;r<4;r++){
        int row = w*16 + quad*4 + r;
        lP[row*64 + ((ch ^ (row&7))&7)*8 + (lm&7)] = f2bf(s[j][r]);
      }
    }
    __syncthreads();
    __builtin_amdgcn_s_setprio(1);
    #pragma unroll
    for (int kk=0; kk<2; kk++){
      bf16x8 pa = ldfrag(lP, w*16+lm, kk*4+quad);
      #pragma unroll
      for (int j=0;j<4;j++)
        O[j] = __builtin_amdgcn_mfma_f32_16x16x32_bf16(pa, ldfrag(lV, j*16+lm, kk*4+quad), O[j], 0,0,0);
    }
    __builtin_amdgcn_s_setprio(0);
  }
  size_t obase = (size_t)(b*T_ + qt*64)*D_ + h*64;
  #pragma unroll
  for (int r=0;r<4;r++){
    float inv = 1.0f / l[r];
    #pragma unroll
    for (int j=0;j<4;j++)
      out[obase + (size_t)(w*16+quad*4+r)*D_ + j*16 + lm] = f2bf(O[j][r]*inv);
  }
}

// ---------------- loss from per-block expsum partials (reads 3.2 MB, not 412 MB) -----
__global__ __launch_bounds__(256) void loss_row2_k(const float* __restrict__ stats, int nb,
                                                   const float* __restrict__ logits,
                                                   const int* __restrict__ targets,
                                                   float* __restrict__ rowloss){
  __shared__ float ssm[4];
  int mrow = blockIdx.x, t = threadIdx.x;
  const float* p = stats + (size_t)mrow*nb;
  float s = 0.f;
  for (int i=t;i<nb;i+=256) s += p[i];
  for (int o=32;o;o>>=1) s += __shfl_down(s,o,64);
  if ((t&63)==0) ssm[t>>6]=s;
  __syncthreads();
  if (t==0){
    float gs = ssm[0]+ssm[1]+ssm[2]+ssm[3];
    rowloss[mrow] = logf(gs) - logits[(size_t)mrow*V_ + targets[mrow]];
  }
}

__global__ void loss_reduce_k(const float* __restrict__ rowloss, float* __restrict__ out){
  __shared__ float sm[4];
  int t = threadIdx.x;
  float s = 0.f;
  for (int i=t;i<M_;i+=256) s += rowloss[i];
  for (int o=32;o;o>>=1) s += __shfl_down(s,o,64);
  if ((t&63)==0) sm[t>>6]=s;
  __syncthreads();
  if (t==0) out[0] = (sm[0]+sm[1]+sm[2]+sm[3])*(1.0f/M_);
}

// ---------------- launch ----------------
extern "C" void kernel_launch(void* const* d_in, const int* in_sizes, int n_in,
                              void* d_out, int out_size, void* d_ws, size_t ws_size,
                              hipStream_t stream) {
  const int*   idx     = (const int*)d_in[0];
  const int*   targets = (const int*)d_in[1];
  const float* wte     = (const float*)d_in[2];
  const float* wpe     = (const float*)d_in[3];
  const float* ln1_w   = (const float*)d_in[4];
  const float* ln1_b   = (const float*)d_in[5];
  const float* attn_w  = (const float*)d_in[6];
  const float* attn_b  = (const float*)d_in[7];
  const float* proj_w  = (const float*)d_in[8];
  const float* proj_b  = (const float*)d_in[9];
  const float* ln2_w   = (const float*)d_in[10];
  const float* ln2_b   = (const float*)d_in[11];
  const float* fc_w    = (const float*)d_in[12];
  const float* fc_b    = (const float*)d_in[13];
  const float* fcp_w   = (const float*)d_in[14];
  const float* fcp_b   = (const float*)d_in[15];
  const float* lnf_w   = (const float*)d_in[16];
  const float* lnf_b   = (const float*)d_in[17];

  const int NBY = (V_+127)/128;  // 393 lm-head N-blocks

  char* ws = (char*)d_ws;
  size_t off = 0;
  auto alloc = [&](size_t bytes)->void*{ void* p = ws + off; off += (bytes + 255) & ~(size_t)255; return p; };
  u16*   wte_bf  = (u16*)  alloc((size_t)V_*D_*2);
  u16*   aw_bf   = (u16*)  alloc((size_t)L_*3*D_*D_*2);
  u16*   pw_bf   = (u16*)  alloc((size_t)L_*D_*D_*2);
  u16*   fw_bf   = (u16*)  alloc((size_t)L_*4*D_*D_*2);
  u16*   fpw_bf  = (u16*)  alloc((size_t)L_*D_*4*D_*2);
  float* xb      = (float*)alloc((size_t)M_*D_*4);
  u16*   actA    = (u16*)  alloc((size_t)M_*4*D_*2);
  u16*   actB    = (u16*)  alloc((size_t)M_*4*D_*2);
  u16*   qkv_bf  = (u16*)  alloc((size_t)M_*3*D_*2);
  u16*   vt_bf   = (u16*)  alloc((size_t)B_*H_*64*T_*2);
  float* stats   = (float*)alloc((size_t)M_*NBY*4);
  float* rowloss = (float*)alloc((size_t)M_*4);
  (void)ws_size; (void)in_sizes; (void)n_in; (void)out_size;

  auto cvt = [&](const float* in, u16* out, size_t n){
    int n4 = (int)(n/4);
    cvt_bf16x4<<<dim3((n4+255)/256), dim3(256), 0, stream>>>((const float4*)in, (ushort4*)out, n4);
  };
  cvt(wte,    wte_bf, (size_t)V_*D_);
  cvt(attn_w, aw_bf,  (size_t)L_*3*D_*D_);
  cvt(proj_w, pw_bf,  (size_t)L_*D_*D_);
  cvt(fc_w,   fw_bf,  (size_t)L_*4*D_*D_);
  cvt(fcp_w,  fpw_bf, (size_t)L_*D_*4*D_);

  embed_k<<<M_, 256, 0, stream>>>(idx, wte, wpe, xb);

  for (int l=0; l<L_; l++){
    ln_k<<<M_, 256, 0, stream>>>(xb, ln1_w + l*D_, ln1_b + l*D_, actA);
    gemm_bt<0,u16,false><<<dim3(16,24), 256, 0, stream>>>(
        actA, aw_bf + (size_t)l*3*D_*D_, attn_b + l*3*D_, nullptr, qkv_bf, nullptr, M_, 3*D_, D_);
    vt_k<<<B_*H_*16, 256, 0, stream>>>(qkv_bf, vt_bf);
    attn_k<<<B_*H_*16, 256, 0, stream>>>(qkv_bf, vt_bf, actA);
    // proj: split-K x2 atomic-accumulate into xb (xb already holds residual x)
    gemm_bt<4,float,false><<<dim3(16,8,2), 256, 0, stream>>>(
        actA, pw_bf + (size_t)l*D_*D_, proj_b + l*D_, nullptr, xb, nullptr, M_, D_, D_);
    ln_k<<<M_, 256, 0, stream>>>(xb, ln2_w + l*D_, ln2_b + l*D_, actA);
    gemm_bt<2,u16,false><<<dim3(16,32), 256, 0, stream>>>(
        actA, fw_bf + (size_t)l*4*D_*D_, fc_b + l*4*D_, nullptr, actB, nullptr, M_, 4*D_, D_);
    // fcp: split-K x4 atomic-accumulate into xb
    gemm_bt<4,float,false><<<dim3(16,8,4), 256, 0, stream>>>(
        actB, fpw_bf + (size_t)l*D_*4*D_, fcp_b + l*D_, nullptr, xb, nullptr, M_, D_, 4*D_);
  }

  ln_k<<<M_, 256, 0, stream>>>(xb, lnf_w, lnf_b, actA);
  float* logits = (float*)d_out;
  gemm_bt<3,float,true><<<dim3(16, NBY), 256, 0, stream>>>(
      actA, wte_bf, nullptr, nullptr, logits, stats, M_, V_, D_);
  loss_row2_k<<<M_, 256, 0, stream>>>(stats, NBY, logits, targets, rowloss);
  loss_reduce_k<<<1, 256, 0, stream>>>(rowloss, logits + (size_t)M_*V_);
}

// Round 5
// 2316.121 us; speedup vs baseline: 1.7045x; 1.0919x over previous
//
#include <hip/hip_runtime.h>
#include <hip/hip_bf16.h>
#include <math.h>

#define L_ 6
#define H_ 16
#define D_ 1024
#define V_ 50257
#define B_ 2
#define T_ 1024
#define M_ (B_*T_)

typedef unsigned short u16;
typedef __attribute__((ext_vector_type(8))) __bf16 bf16x8;
typedef __attribute__((ext_vector_type(8))) unsigned short u16x8;
typedef __attribute__((ext_vector_type(4))) float f32x4;

__device__ __forceinline__ u16 f2bf(float x){
  union { __hip_bfloat16 h; u16 u; } c;
  c.h = __float2bfloat16(x);
  return c.u;
}

__device__ __forceinline__ void gload_lds16(const void* g, void* l){
  __builtin_amdgcn_global_load_lds(
      (__attribute__((address_space(1))) void*)(const_cast<void*>(g)),
      (__attribute__((address_space(3))) void*)l, 16, 0, 0);
}

// ---------------- fp32 -> bf16 weight conversion ----------------
__global__ void cvt_bf16x4(const float4* __restrict__ in, ushort4* __restrict__ out, int n4){
  int i = blockIdx.x*256 + threadIdx.x;
  if (i < n4){
    float4 v = in[i];
    ushort4 o;
    o.x = f2bf(v.x); o.y = f2bf(v.y); o.z = f2bf(v.z); o.w = f2bf(v.w);
    out[i] = o;
  }
}

// ---------------- embedding ----------------
__global__ __launch_bounds__(256) void embed_k(const int* __restrict__ idx, const float* __restrict__ wte,
                        const float* __restrict__ wpe, float* __restrict__ xb){
  int m = blockIdx.x;
  int t = m % T_;
  int tok = idx[m];
  const float4* w = (const float4*)(wte + (size_t)tok*D_);
  const float4* p = (const float4*)(wpe + (size_t)t*D_);
  float4* o = (float4*)(xb + (size_t)m*D_);
  int d = threadIdx.x;
  float4 a = w[d], b = p[d];
  o[d] = make_float4(a.x+b.x, a.y+b.y, a.z+b.z, a.w+b.w);
}

// ---------------- layernorm (fp32 in, bf16 out) ----------------
__global__ __launch_bounds__(256) void ln_k(const float* __restrict__ x, const float* __restrict__ w,
                     const float* __restrict__ b, u16* __restrict__ out){
  __shared__ float sm[8];
  int m = blockIdx.x, t = threadIdx.x;
  const float4* xr = (const float4*)(x + (size_t)m*D_);
  float4 v = xr[t];
  float s  = v.x+v.y+v.z+v.w;
  float ss = v.x*v.x+v.y*v.y+v.z*v.z+v.w*v.w;
  for (int o=32;o;o>>=1){ s += __shfl_down(s,o,64); ss += __shfl_down(ss,o,64); }
  if ((t&63)==0){ sm[t>>6]=s; sm[4+(t>>6)]=ss; }
  __syncthreads();
  s  = sm[0]+sm[1]+sm[2]+sm[3];
  ss = sm[4]+sm[5]+sm[6]+sm[7];
  float mean = s*(1.0f/D_);
  float var  = ss*(1.0f/D_) - mean*mean;
  float rstd = rsqrtf(var + 1e-5f);
  float4 wv = ((const float4*)w)[t];
  float4 bv = ((const float4*)b)[t];
  ushort4 o4;
  o4.x = f2bf((v.x-mean)*rstd*wv.x + bv.x);
  o4.y = f2bf((v.y-mean)*rstd*wv.y + bv.y);
  o4.z = f2bf((v.z-mean)*rstd*wv.z + bv.z);
  o4.w = f2bf((v.w-mean)*rstd*wv.w + bv.w);
  ((ushort4*)(out + (size_t)m*D_))[t] = o4;
}

// ---------------- GEMM: C[M,N] = A[M,K] * W[N,K]^T (m97 structure, layer GEMMs) ------
// KIND: 0=plain store, 1=+resid store, 2=gelu store,
//       4=split-K atomicAdd accumulate into C (C pre-holds residual; bias from z==0).
__device__ __forceinline__ void storeval(float* C, size_t i, float v){ C[i] = v; }
__device__ __forceinline__ void storeval(u16*   C, size_t i, float v){ C[i] = f2bf(v); }

template<int KIND, typename OUT_T, bool NB>
__global__ __launch_bounds__(256) void gemm_bt(const u16* __restrict__ A, const u16* __restrict__ W,
    const float* __restrict__ bias, const float* __restrict__ resid,
    OUT_T* __restrict__ C, float* __restrict__ stats, int M, int N, int K)
{
  __shared__ u16 lA[128*64];
  __shared__ u16 lB[128*64];
  int t = threadIdx.x;
  int m0 = blockIdx.x*128, n0 = blockIdx.y*128;
  int w = t>>6, lane = t&63, quad = lane>>4, lm = lane&15;
  int wr = w>>1, wc = w&1;
  int arow = t>>3, aseg = t&7;
  int kbeg = 0, kend = K;
  if (KIND==4){
    int ks = K / gridDim.z;
    kbeg = blockIdx.z * ks; kend = kbeg + ks;
  }
  f32x4 acc[4][4] = {};
  for (int k0 = kbeg; k0 < kend; k0 += 64){
    __syncthreads();
    #pragma unroll
    for (int it=0; it<4; it++){
      gload_lds16(A + (size_t)(m0 + it*32 + arow)*K + k0 + aseg*8, &lA[it*2048 + t*8]);
      int br = n0 + it*32 + arow;
      if (NB) br = (br < N) ? br : (N-1);
      gload_lds16(W + (size_t)br*K + k0 + aseg*8, &lB[it*2048 + t*8]);
    }
    __syncthreads();
    #pragma unroll
    for (int kk=0; kk<64; kk+=32){
      bf16x8 af[4], bfr[4];
      #pragma unroll
      for (int i=0;i<4;i++) af[i]  = *(const bf16x8*)&lA[(wr*64+i*16+lm)*64 + kk + quad*8];
      #pragma unroll
      for (int j=0;j<4;j++) bfr[j] = *(const bf16x8*)&lB[(wc*64+j*16+lm)*64 + kk + quad*8];
      #pragma unroll
      for (int i=0;i<4;i++)
        #pragma unroll
        for (int j=0;j<4;j++)
          acc[i][j] = __builtin_amdgcn_mfma_f32_16x16x32_bf16(af[i], bfr[j], acc[i][j], 0,0,0);
    }
  }
  #pragma unroll
  for (int i=0;i<4;i++){
    int mb = m0 + wr*64 + i*16 + quad*4;
    #pragma unroll
    for (int j=0;j<4;j++){
      int n = n0 + wc*64 + j*16 + lm;
      bool valid = !(NB && n >= N);
      float bv = 0.0f;
      if (bias && valid){ if (KIND!=4 || blockIdx.z==0) bv = bias[n]; }
      #pragma unroll
      for (int r=0;r<4;r++){
        float v = acc[i][j][r] + bv;
        int mm = mb + r;
        size_t cix = (size_t)mm*(size_t)N + n;
        if constexpr (KIND==1) v += resid[cix];
        if constexpr (KIND==2) v = 0.5f*v*(1.0f + erff(v*0.70710678118654752f));
        if constexpr (KIND==4){
          if (valid) atomicAdd((float*)&C[cix], v);
        } else {
          if (valid) storeval(C, cix, v);
        }
      }
    }
  }
  (void)stats;
}

// ---------------- lm-head GEMM: 256x256 tile, 8 waves, ring-4 deep pipeline ----------
// C[M,N] = A[M,K]*W[N,K]^T (fp32 out) + per-block expsum row partials for the loss.
// K split into NS=K/32 subs (one mfma k-depth each). LDS = ring of 4 sub-slots per
// operand (4 x 16KB x 2 = 128KB, 1 block/CU, 8 waves). Staging runs 3 subs ahead;
// slot(s+3) never aliases slots {s,s+1,s+2}, and the per-sub barrier bounds wave
// drift so stage(s+4) can't race readers of slot(s&3). Gate = counted
// s_waitcnt vmcnt(8) (2 sub-stages stay IN FLIGHT across the raw s_barrier -- T3/T4),
// + sched_barrier(0) compiler fence (rule 18). Chunk swizzle c^=(row&3): inverse
// applied on the GLOBAL source (gload_lds dest must stay linear, rule 21), same
// involution on the ds_read side.
__global__ __launch_bounds__(512) void gemm_lm(const u16* __restrict__ A, const u16* __restrict__ W,
    float* __restrict__ C, float* __restrict__ stats, int M, int N, int K)
{
  __shared__ __align__(16) u16 lds[65536];   // 128 KB: lA = [0,32768), lB = [32768,65536)
  u16* lA = lds;
  u16* lB = lds + 32768;
  int t = threadIdx.x;
  int m0 = blockIdx.x*256, n0 = blockIdx.y*256;
  int wid = t>>6, lane = t&63, quad = lane>>4, lm = lane&15;
  int wm = wid>>2, wn = wid&3;
  const int NS = K>>5;           // 32 K-subs of 32
  f32x4 acc[8][4] = {};

  auto stage = [&](int s){       // 4 gload_lds/thread into slot s&3
    int k0 = s*32;
    u16* As = lA + (s&3)*8192;
    u16* Bs = lB + (s&3)*8192;
    #pragma unroll
    for (int h=0; h<2; h++){
      int sl = t + h*512;        // 0..1023 16B-chunks, linear LDS raster
      int row = sl>>2, c = sl&3;
      int cs = (c ^ row) & 3;    // inverse swizzle on the global source
      gload_lds16(A + (size_t)(m0+row)*K + k0 + cs*8, As + sl*8);
      int br = n0 + row; br = br < N ? br : N-1;
      gload_lds16(W + (size_t)br*K + k0 + cs*8, Bs + sl*8);
    }
  };
  auto compute = [&](int s){
    const u16* As = lA + (s&3)*8192;
    const u16* Bs = lB + (s&3)*8192;
    bf16x8 bfr[4];
    #pragma unroll
    for (int j=0;j<4;j++){
      int rw = wn*64 + j*16 + lm;
      bfr[j] = *(const bf16x8*)&Bs[rw*32 + ((quad ^ rw)&3)*8];
    }
    #pragma unroll
    for (int ih=0; ih<2; ih++){
      bf16x8 af[4];
      #pragma unroll
      for (int ii=0;ii<4;ii++){
        int rw = wm*128 + (ih*4+ii)*16 + lm;
        af[ii] = *(const bf16x8*)&As[rw*32 + ((quad ^ rw)&3)*8];
      }
      __builtin_amdgcn_s_setprio(1);
      #pragma unroll
      for (int ii=0;ii<4;ii++)
        #pragma unroll
        for (int j=0;j<4;j++)
          acc[ih*4+ii][j] = __builtin_amdgcn_mfma_f32_16x16x32_bf16(af[ii], bfr[j], acc[ih*4+ii][j], 0,0,0);
      __builtin_amdgcn_s_setprio(0);
    }
  };

  stage(0); stage(1); stage(2);
  for (int s = 0; s < NS-3; s++){
    asm volatile("s_waitcnt vmcnt(8)" ::: "memory");   // sub s resident; 2 stages in flight
    __builtin_amdgcn_s_barrier();
    __builtin_amdgcn_sched_barrier(0);
    stage(s+3);
    compute(s);
  }
  asm volatile("s_waitcnt vmcnt(8)" ::: "memory");
  __builtin_amdgcn_s_barrier();
  __builtin_amdgcn_sched_barrier(0);
  compute(NS-3);
  asm volatile("s_waitcnt vmcnt(4)" ::: "memory");
  __builtin_amdgcn_s_barrier();
  __builtin_amdgcn_sched_barrier(0);
  compute(NS-2);
  asm volatile("s_waitcnt vmcnt(0)" ::: "memory");
  __builtin_amdgcn_s_barrier();
  __builtin_amdgcn_sched_barrier(0);
  compute(NS-1);

  // epilogue: C store + per-row expsum partials (max-free; logits bounded)
  __syncthreads();
  float* lsum = (float*)lA;      // overlay: [256 rows][4 wn]
  int c0 = n0 + wn*64;
  #pragma unroll
  for (int i=0;i<8;i++){
    #pragma unroll
    for (int r=0;r<4;r++){
      int rloc = wm*128 + i*16 + quad*4 + r;
      int mm = m0 + rloc;
      float ps = 0.f;
      #pragma unroll
      for (int j=0;j<4;j++){
        int n = c0 + j*16 + lm;
        float v = acc[i][j][r];
        if (n < N){ C[(size_t)mm*(size_t)N + n] = v; ps += __expf(v); }
      }
      #pragma unroll
      for (int o=1;o<16;o<<=1) ps += __shfl_xor(ps, o, 16);
      if (lm==0) lsum[rloc*4 + wn] = ps;
    }
  }
  __syncthreads();
  if (t < 256)
    stats[(size_t)(m0+t)*gridDim.y + blockIdx.y] =
        lsum[t*4] + lsum[t*4+1] + lsum[t*4+2] + lsum[t*4+3];
}

// ---------------- attention helpers: swizzled 64x64 bf16 LDS tiles ----------------
__device__ __forceinline__ void stage64(u16* lds, const u16* g, size_t rowstride){
  int t = threadIdx.x;
  #pragma unroll
  for (int ch = t; ch < 512; ch += 256){
    int row = ch>>3, seg = ch&7;
    int sw = seg ^ (row & 7);
    *(u16x8*)&lds[row*64 + sw*8] = *(const u16x8*)(g + (size_t)row*rowstride + seg*8);
  }
}
__device__ __forceinline__ bf16x8 ldfrag(const u16* lds, int r, int c){
  return *(const bf16x8*)&lds[r*64 + ((c ^ (r&7))&7)*8];
}

// ---------------- V transpose: vt[bh][d][k] bf16 (makes PV B-operand K-major) --------
__global__ __launch_bounds__(256) void vt_k(const u16* __restrict__ qkv, u16* __restrict__ vt){
  __shared__ u16 lT[4096];   // [64 k][64 d], chunk-swizzled by (k>>3)
  int blk = blockIdx.x;
  int kt = blk & 15, bh = blk >> 4;
  int b = bh >> 4, h = bh & 15;
  int t = threadIdx.x;
  #pragma unroll
  for (int ch = t; ch < 512; ch += 256){
    int row = ch>>3, seg = ch&7;
    int sw = seg ^ (row>>3);
    const u16* src = qkv + (size_t)(b*T_ + kt*64 + row)*3072 + 2048 + h*64 + seg*8;
    *(u16x8*)&lT[row*64 + sw*8] = *(const u16x8*)src;
  }
  __syncthreads();
  #pragma unroll
  for (int ch = t; ch < 512; ch += 256){
    int d = ch>>3, sk = ch&7;
    u16x8 o;
    #pragma unroll
    for (int i=0;i<8;i++){
      int k = sk*8 + i;
      o[i] = lT[k*64 + ((((d>>3) ^ sk)&7)*8) + (d&7)];
    }
    *(u16x8*)(vt + (size_t)(bh*64 + d)*T_ + kt*64 + sk*8) = o;
  }
}

// ---------------- fused flash attention: QK^T -> online softmax -> PV ----------------
__global__ __launch_bounds__(256) void attn_k(const u16* __restrict__ qkv, const u16* __restrict__ vt,
                                              u16* __restrict__ out){
  __shared__ u16 lQ[4096], lK[4096], lV[4096], lP[4096];
  int blk = blockIdx.x;
  int qt = blk & 15, bh = blk >> 4;
  int b = bh >> 4, h = bh & 15;
  int t = threadIdx.x, w = t>>6, lane = t&63, quad = lane>>4, lm = lane&15;
  const u16* qbase = qkv + (size_t)(b*T_ + qt*64)*3072 + h*64;
  const u16* kbase = qkv + (size_t)b*T_*3072 + 1024 + h*64;
  const u16* vbase = vt + (size_t)bh*64*T_;
  stage64(lQ, qbase, 3072);
  f32x4 O[4] = {};
  float m[4], l[4];
  #pragma unroll
  for (int r=0;r<4;r++){ m[r] = -1e30f; l[r] = 0.f; }
  for (int kt=0; kt<=qt; kt++){
    __syncthreads();   // prior iter's lK/lV/lP reads done
    stage64(lK, kbase + (size_t)kt*64*3072, 3072);
    stage64(lV, vbase + kt*64, T_);
    __syncthreads();
    f32x4 s[4] = {};
    __builtin_amdgcn_s_setprio(1);
    #pragma unroll
    for (int kk=0; kk<2; kk++){
      bf16x8 af = ldfrag(lQ, w*16+lm, kk*4+quad);
      #pragma unroll
      for (int j=0;j<4;j++)
        s[j] = __builtin_amdgcn_mfma_f32_16x16x32_bf16(af, ldfrag(lK, j*16+lm, kk*4+quad), s[j], 0,0,0);
    }
    __builtin_amdgcn_s_setprio(0);
    int qrow = qt*64 + w*16 + quad*4;
    #pragma unroll
    for (int r=0;r<4;r++){
      float mx = -1e30f;
      #pragma unroll
      for (int j=0;j<4;j++){
        int k = kt*64 + j*16 + lm;
        float v = (k <= qrow + r) ? s[j][r]*0.125f : -1e30f;
        s[j][r] = v;
        mx = fmaxf(mx, v);
      }
      #pragma unroll
      for (int o=1;o<16;o<<=1) mx = fmaxf(mx, __shfl_xor(mx, o, 16));
      float mn = fmaxf(m[r], mx);
      float sc = expf(m[r] - mn);
      float ps = 0.f;
      #pragma unroll
      for (int j=0;j<4;j++){
        float p = expf(s[j][r] - mn);
        s[j][r] = p; ps += p;
      }
      #pragma unroll
      for (int o=1;o<16;o<<=1) ps += __shfl_xor(ps, o, 16);
      l[r] = l[r]*sc + ps; m[r] = mn;
      O[0][r] *= sc; O[1][r] *= sc; O[2][r] *= sc; O[3][r] *= sc;
    }
    // P -> LDS (bf16, same swizzle convention as stage64/ldfrag)
    #pragma unroll
    for (int j=0;j<4;j++){
      int ch = j*2 + (lm>>3);
      #pragma unroll
      for (int r=0;r<4;r++){
        int row = w*16 + quad*4 + r;
        lP[row*64 + ((ch ^ (row&7))&7)*8 + (lm&7)] = f2bf(s[j][r]);
      }
    }
    __syncthreads();
    __builtin_amdgcn_s_setprio(1);
    #pragma unroll
    for (int kk=0; kk<2; kk++){
      bf16x8 pa = ldfrag(lP, w*16+lm, kk*4+quad);
      #pragma unroll
      for (int j=0;j<4;j++)
        O[j] = __builtin_amdgcn_mfma_f32_16x16x32_bf16(pa, ldfrag(lV, j*16+lm, kk*4+quad), O[j], 0,0,0);
    }
    __builtin_amdgcn_s_setprio(0);
  }
  size_t obase = (size_t)(b*T_ + qt*64)*D_ + h*64;
  #pragma unroll
  for (int r=0;r<4;r++){
    float inv = 1.0f / l[r];
    #pragma unroll
    for (int j=0;j<4;j++)
      out[obase + (size_t)(w*16+quad*4+r)*D_ + j*16 + lm] = f2bf(O[j][r]*inv);
  }
}

// ---------------- loss from per-block expsum partials ----------------
__global__ __launch_bounds__(256) void loss_row2_k(const float* __restrict__ stats, int nb,
                                                   const float* __restrict__ logits,
                                                   const int* __restrict__ targets,
                                                   float* __restrict__ rowloss){
  __shared__ float ssm[4];
  int mrow = blockIdx.x, t = threadIdx.x;
  const float* p = stats + (size_t)mrow*nb;
  float s = 0.f;
  for (int i=t;i<nb;i+=256) s += p[i];
  for (int o=32;o;o>>=1) s += __shfl_down(s,o,64);
  if ((t&63)==0) ssm[t>>6]=s;
  __syncthreads();
  if (t==0){
    float gs = ssm[0]+ssm[1]+ssm[2]+ssm[3];
    rowloss[mrow] = logf(gs) - logits[(size_t)mrow*V_ + targets[mrow]];
  }
}

__global__ void loss_reduce_k(const float* __restrict__ rowloss, float* __restrict__ out){
  __shared__ float sm[4];
  int t = threadIdx.x;
  float s = 0.f;
  for (int i=t;i<M_;i+=256) s += rowloss[i];
  for (int o=32;o;o>>=1) s += __shfl_down(s,o,64);
  if ((t&63)==0) sm[t>>6]=s;
  __syncthreads();
  if (t==0) out[0] = (sm[0]+sm[1]+sm[2]+sm[3])*(1.0f/M_);
}

// ---------------- launch ----------------
extern "C" void kernel_launch(void* const* d_in, const int* in_sizes, int n_in,
                              void* d_out, int out_size, void* d_ws, size_t ws_size,
                              hipStream_t stream) {
  const int*   idx     = (const int*)d_in[0];
  const int*   targets = (const int*)d_in[1];
  const float* wte     = (const float*)d_in[2];
  const float* wpe     = (const float*)d_in[3];
  const float* ln1_w   = (const float*)d_in[4];
  const float* ln1_b   = (const float*)d_in[5];
  const float* attn_w  = (const float*)d_in[6];
  const float* attn_b  = (const float*)d_in[7];
  const float* proj_w  = (const float*)d_in[8];
  const float* proj_b  = (const float*)d_in[9];
  const float* ln2_w   = (const float*)d_in[10];
  const float* ln2_b   = (const float*)d_in[11];
  const float* fc_w    = (const float*)d_in[12];
  const float* fc_b    = (const float*)d_in[13];
  const float* fcp_w   = (const float*)d_in[14];
  const float* fcp_b   = (const float*)d_in[15];
  const float* lnf_w   = (const float*)d_in[16];
  const float* lnf_b   = (const float*)d_in[17];

  const int NBY = (V_+255)/256;  // 197 lm-head N-blocks

  char* ws = (char*)d_ws;
  size_t off = 0;
  auto alloc = [&](size_t bytes)->void*{ void* p = ws + off; off += (bytes + 255) & ~(size_t)255; return p; };
  u16*   wte_bf  = (u16*)  alloc((size_t)V_*D_*2);
  u16*   aw_bf   = (u16*)  alloc((size_t)L_*3*D_*D_*2);
  u16*   pw_bf   = (u16*)  alloc((size_t)L_*D_*D_*2);
  u16*   fw_bf   = (u16*)  alloc((size_t)L_*4*D_*D_*2);
  u16*   fpw_bf  = (u16*)  alloc((size_t)L_*D_*4*D_*2);
  float* xb      = (float*)alloc((size_t)M_*D_*4);
  u16*   actA    = (u16*)  alloc((size_t)M_*4*D_*2);
  u16*   actB    = (u16*)  alloc((size_t)M_*4*D_*2);
  u16*   qkv_bf  = (u16*)  alloc((size_t)M_*3*D_*2);
  u16*   vt_bf   = (u16*)  alloc((size_t)B_*H_*64*T_*2);
  float* stats   = (float*)alloc((size_t)M_*NBY*4);
  float* rowloss = (float*)alloc((size_t)M_*4);
  (void)ws_size; (void)in_sizes; (void)n_in; (void)out_size;

  auto cvt = [&](const float* in, u16* out, size_t n){
    int n4 = (int)(n/4);
    cvt_bf16x4<<<dim3((n4+255)/256), dim3(256), 0, stream>>>((const float4*)in, (ushort4*)out, n4);
  };
  cvt(wte,    wte_bf, (size_t)V_*D_);
  cvt(attn_w, aw_bf,  (size_t)L_*3*D_*D_);
  cvt(proj_w, pw_bf,  (size_t)L_*D_*D_);
  cvt(fc_w,   fw_bf,  (size_t)L_*4*D_*D_);
  cvt(fcp_w,  fpw_bf, (size_t)L_*D_*4*D_);

  embed_k<<<M_, 256, 0, stream>>>(idx, wte, wpe, xb);

  for (int l=0; l<L_; l++){
    ln_k<<<M_, 256, 0, stream>>>(xb, ln1_w + l*D_, ln1_b + l*D_, actA);
    gemm_bt<0,u16,false><<<dim3(16,24), 256, 0, stream>>>(
        actA, aw_bf + (size_t)l*3*D_*D_, attn_b + l*3*D_, nullptr, qkv_bf, nullptr, M_, 3*D_, D_);
    vt_k<<<B_*H_*16, 256, 0, stream>>>(qkv_bf, vt_bf);
    attn_k<<<B_*H_*16, 256, 0, stream>>>(qkv_bf, vt_bf, actA);
    // proj: split-K x2 atomic-accumulate into xb (xb already holds residual x)
    gemm_bt<4,float,false><<<dim3(16,8,2), 256, 0, stream>>>(
        actA, pw_bf + (size_t)l*D_*D_, proj_b + l*D_, nullptr, xb, nullptr, M_, D_, D_);
    ln_k<<<M_, 256, 0, stream>>>(xb, ln2_w + l*D_, ln2_b + l*D_, actA);
    gemm_bt<2,u16,false><<<dim3(16,32), 256, 0, stream>>>(
        actA, fw_bf + (size_t)l*4*D_*D_, fc_b + l*4*D_, nullptr, actB, nullptr, M_, 4*D_, D_);
    // fcp: split-K x4 atomic-accumulate into xb
    gemm_bt<4,float,false><<<dim3(16,8,4), 256, 0, stream>>>(
        actB, fpw_bf + (size_t)l*D_*4*D_, fcp_b + l*D_, nullptr, xb, nullptr, M_, D_, 4*D_);
  }

  ln_k<<<M_, 256, 0, stream>>>(xb, lnf_w, lnf_b, actA);
  float* logits = (float*)d_out;
  gemm_lm<<<dim3(8, NBY), 512, 0, stream>>>(actA, wte_bf, logits, stats, M_, V_, D_);
  loss_row2_k<<<M_, 256, 0, stream>>>(stats, NBY, logits, targets, rowloss);
  loss_reduce_k<<<1, 256, 0, stream>>>(rowloss, logits + (size_t)M_*V_);
}